// Round 15
// baseline (502.717 us; speedup 1.0000x reference)
//
#include <hip/hip_runtime.h>
#include <hip/hip_bf16.h>

typedef __attribute__((ext_vector_type(4))) float f32x4;
typedef __attribute__((ext_vector_type(8))) short short8;
typedef __attribute__((ext_vector_type(8))) __bf16 bf16x8;

#define NDIM 172
#define EDIM 172
#define TDIM 100
#define KCAT 444   // 172+172+100
#define QDIM 272   // 172+100
#define ODIM 128
#define ZDIM 256
#define NNBR 32
#define NPH 14     // K=32 phases (448 padded)
#define NT 7       // K=64 tiles
#define RPB 8      // batch rows per block
#define LN_EPS 1e-5f

// ---- LDS map (dynamic, ~82 KB, 1 block/CU of 16 waves) ----
#define Z_OFF    0         // Z bf16 [128][256] ZB-swizzled (4-row tail groups)
#define A_OFF    65536     // A exchange: 2 slots x 4 KB bf16 [32][64] swizzled
#define QRES_OFF 73728     // [8][128] f32
#define MASK_OFF 77824     // [8][32] int
#define PB_OFF   78848     // [4][2][32] f32
#define OB_OFF   79872     // [4][128] f32
#define RED_OFF  81920     // [16][2] f32
#define SMEM_BYTES 82048

#define ZB(r,c) ((((r) * 512) + ((c) * 2)) ^ (((r) & 7) << 4))

// lgkm-only barrier: vmcnt (the deep A-load pipeline) stays in flight
#define BARRIER() do { \
    asm volatile("s_waitcnt lgkmcnt(0)\ns_barrier" ::: "memory"); \
    __builtin_amdgcn_sched_barrier(0); \
} while (0)

__device__ __forceinline__ unsigned short f2bf(float f) {
    unsigned u = __builtin_bit_cast(unsigned, f);
    u += 0x7fffu + ((u >> 16) & 1u);
    return (unsigned short)(u >> 16);
}
__device__ __forceinline__ float bf2f(unsigned short h) {
    unsigned u = ((unsigned)h) << 16;
    return __builtin_bit_cast(float, u);
}
__device__ __forceinline__ unsigned short bfb(float f) {
    return __builtin_bit_cast(unsigned short, (__bf16)f);
}

// ---- prep: wfrag = Wkv bf16 in MFMA B-fragment order (R7 layout):
// [phase 0..13][n16 0..15][lane 0..63][8]; row=n16*16+(l&15), k=phase*32+(l>>4)*8+e
#define WFRAG_N (NPH * 8192)        // 114688 shorts
#define WQT_N (QDIM * ODIM)         // 34816
#define WOT_N (ODIM * ODIM)         // 16384
__global__ void prep_pack(const float* __restrict__ Wkv, const float* __restrict__ Wq,
                          const float* __restrict__ Wo,
                          unsigned short* __restrict__ wfrag,
                          unsigned short* __restrict__ wqT,
                          unsigned short* __restrict__ woT) {
    int idx = blockIdx.x * 256 + threadIdx.x;
    if (idx < WFRAG_N) {
        int phase = idx >> 13;
        int r = idx & 8191;
        int n16 = r >> 9;
        int q = r & 511;
        int l = q >> 3, e = q & 7;
        int row = n16 * 16 + (l & 15);
        int k = phase * 32 + ((l >> 4) << 3) + e;
        wfrag[idx] = f2bf(k < KCAT ? Wkv[row * KCAT + k] : 0.f);
    } else if (idx < WFRAG_N + WQT_N) {
        int j = idx - WFRAG_N;
        int k = j >> 7, c = j & 127;
        wqT[j] = f2bf(Wq[c * QDIM + k]);
    } else if (idx < WFRAG_N + WQT_N + WOT_N) {
        int j = idx - WFRAG_N - WQT_N;
        int k = j >> 7, c = j & 127;
        woT[j] = f2bf(Wo[c * ODIM + k]);
    }
}

// ---- Q projection (unchanged, proven)
__global__ __launch_bounds__(256) void q_proj(
    const float* __restrict__ node_feat, const float* __restrict__ time_feat,
    const unsigned short* __restrict__ wqT, const float* __restrict__ bq,
    float* __restrict__ Qbuf) {
    __shared__ float x[8][QDIM];
    const int tid = threadIdx.x;
    const long b0 = (long)blockIdx.x * 8;
    for (int g = tid; g < 8 * QDIM; g += 256) {
        int r = g / QDIM, k = g - r * QDIM;
        x[r][k] = (k < NDIM) ? node_feat[(b0 + r) * NDIM + k]
                             : time_feat[(b0 + r) * TDIM + (k - NDIM)];
    }
    __syncthreads();
    const int c = tid & 127;
    const int rb = (tid >> 7) * 4;
    float s0 = bq[c], s1 = s0, s2 = s0, s3 = s0;
    #pragma unroll 8
    for (int k = 0; k < QDIM; k++) {
        float w = bf2f(wqT[k * 128 + c]);
        s0 += x[rb + 0][k] * w;
        s1 += x[rb + 1][k] * w;
        s2 += x[rb + 2][k] * w;
        s3 += x[rb + 3][k] * w;
    }
    Qbuf[(b0 + rb + 0) * 128 + c] = s0;
    Qbuf[(b0 + rb + 1) * 128 + c] = s1;
    Qbuf[(b0 + rb + 2) * 128 + c] = s2;
    Qbuf[(b0 + rb + 3) * 128 + c] = s3;
}

// ---- fused: 1024 thr / 16 waves, each wave a 16-col band. W in registers
// (14 frags = 56 VGPR/wave), A reg-pipelined 7 tiles deep (float2/thread),
// tiny LDS exchange with alternating slot parity, lgkm-only barriers.
// __launch_bounds__(1024, 2): VGPR cap = 256/2 = 128 (R13's (1024,4) capped
// at 64 -> catastrophic spill; the structure needs ~100).
__global__ __launch_bounds__(1024, 2) void ta_fused(
    const float* __restrict__ edge_feat, const float* __restrict__ nbr_node,
    const float* __restrict__ nbr_time, const int* __restrict__ nbr_mask,
    const float* __restrict__ Qbuf,
    const unsigned short* __restrict__ wfrag, const float* __restrict__ bkv,
    const unsigned short* __restrict__ woT, const float* __restrict__ bo,
    const float* __restrict__ gamma, const float* __restrict__ beta,
    float* __restrict__ out)
{
    extern __shared__ __align__(16) unsigned char smem[];
    float* qresL = (float*)(smem + QRES_OFF);
    int*   maskL = (int*)(smem + MASK_OFF);
    float* Pband = (float*)(smem + PB_OFF);
    float* Obuf  = (float*)(smem + OB_OFF);
    float* red   = (float*)(smem + RED_OFF);

    const int tid  = threadIdx.x;
    const int lane = tid & 63;
    const int wid  = tid >> 6;          // 0..15 = 16-col band
    const int b0   = blockIdx.x * RPB;

    // ---- stage masks + Q rows for the block's 8 batch rows
    if (tid < RPB * NNBR) maskL[tid] = nbr_mask[(long)b0 * NNBR + tid];
    qresL[tid] = Qbuf[(long)b0 * ODIM + tid];      // 1024 = 8*128
    __syncthreads();   // one-time full drain, nothing deep in flight yet

    // ---- W fragments into registers (one 16-col band per wave)
    bf16x8 Wr[NPH];
    #pragma unroll
    for (int p = 0; p < NPH; p++)
        Wr[p] = __builtin_bit_cast(bf16x8,
            *(const short8*)(wfrag + ((size_t)(p * 16 + wid) * 512 + lane * 8)));
    const float bkW = bkv[wid * 16 + (lane & 15)];

    // ---- per-thread A geometry: thread = (rowA 0..31, kg 0..31), float2 each
    const int rowA = tid >> 5;
    const int kg   = tid & 31;
    const int awb  = rowA * 128 + ((kg * 4) ^ ((rowA & 7) << 4));

    auto loadA = [&](int riX, int t) -> float2 {
        int k = t * 64 + kg * 2;
        long rg = ((long)b0 + riX) * NNBR + rowA;
        const float* p; int off;
        if (k < NDIM)             { p = nbr_node  + rg * NDIM; off = k; }
        else if (k < NDIM + EDIM) { p = edge_feat + rg * EDIM; off = k - NDIM; }
        else { p = nbr_time + rg * TDIM; off = k - NDIM - EDIM;
               if (off > TDIM - 2) off = TDIM - 2; }   // pad: garbage x W=0
        return *(const float2*)(p + off);
    };

    // ---- prologue: iteration 0's 7 tiles in flight (the latency buffer)
    float2 rs[NT];
    #pragma unroll
    for (int t = 0; t < NT; t++) rs[t] = loadA(0, t);
    __builtin_amdgcn_sched_barrier(0);

    for (int ri = 0; ri < RPB; ri++) {
        const int riN = (ri + 1 < RPB) ? ri + 1 : RPB - 1;  // clamp (extra reads ok)
        const int sp  = ri & 1;        // slot parity alternates per iteration
        f32x4 acc[2];
        acc[0] = (f32x4){0.f, 0.f, 0.f, 0.f};
        acc[1] = (f32x4){0.f, 0.f, 0.f, 0.f};

        #pragma unroll
        for (int t = 0; t < NT; t++) {
            unsigned char* aw = smem + A_OFF + (((t + sp) & 1) ? 4096 : 0);
            // stage tile (ri,t): loaded 7 tiles ago -> counted vmcnt wait
            {
                float2 v = rs[t];
                unsigned w = (unsigned)bfb(v.x) | ((unsigned)bfb(v.y) << 16);
                *(unsigned*)(aw + awb) = w;
            }
            rs[t] = loadA(riN, t);            // refill: iter ri+1, same tile
            __builtin_amdgcn_sched_barrier(0);
            BARRIER();                         // exchange visible; vmem in flight
            // compute tile t: phases 2t, 2t+1 (W from registers)
            #pragma unroll
            for (int kk = 0; kk < 2; kk++) {
                bf16x8 af[2];
                #pragma unroll
                for (int m = 0; m < 2; m++) {
                    int row = m * 16 + (lane & 15);
                    af[m] = __builtin_bit_cast(bf16x8, *(const short8*)(
                        aw + row * 128 + ((kk * 64 + (lane >> 4) * 16) ^ ((row & 7) << 4))));
                }
                acc[0] = __builtin_amdgcn_mfma_f32_16x16x32_bf16(af[0], Wr[t * 2 + kk], acc[0], 0, 0, 0);
                acc[1] = __builtin_amdgcn_mfma_f32_16x16x32_bf16(af[1], Wr[t * 2 + kk], acc[1], 0, 0, 0);
            }
        }

        // ---- dump Z row-block (+bkv); C/D: col=lane&15, row=(lane>>4)*4+j
        const int gi = ri & 3;
        {
            int col = wid * 16 + (lane & 15);
            #pragma unroll
            for (int m = 0; m < 2; m++)
                #pragma unroll
                for (int j = 0; j < 4; j++) {
                    int rowZ = gi * 32 + m * 16 + (lane >> 4) * 4 + j;
                    *(unsigned short*)(smem + ZB(rowZ, col)) = bfb(acc[m][j] + bkW);
                }
        }

        if (gi == 3) {
            const int g = ri >> 2;             // tail group 0/1 (uniform)
            BARRIER();                          // dumps visible; A loads keep flying

            // ---- scores + softmax: waves 0..7 -> (bl=wid>>1, h=wid&1)
            if (wid < 8) {
                int bl = wid >> 1, h = wid & 1;
                int n2 = lane >> 1, half = lane & 1;
                int np = h * 16 + (n2 >> 1);
                int rowZ = bl * NNBR + np;
                int cb = (n2 & 1) * 64 + half * 32;
                const float* q = qresL + (g * 4 + bl) * ODIM + h * 64 + half * 32;
                float s = 0.f;
                #pragma unroll
                for (int j = 0; j < 4; j++) {
                    short8 z8 = *(const short8*)(smem + ZB(rowZ, cb + j * 8));
                    #pragma unroll
                    for (int e = 0; e < 8; e++)
                        s += q[j * 8 + e] * bf2f((unsigned short)z8[e]);
                }
                s += __shfl_xor(s, 1);
                s *= 0.125f;
                if (maskL[(g * 4 + bl) * NNBR + n2] == 0) s = -1e10f;
                float mx = s;
                #pragma unroll
                for (int off = 1; off < 64; off <<= 1) mx = fmaxf(mx, __shfl_xor(mx, off));
                float e = __expf(s - mx);
                float sum = e;
                #pragma unroll
                for (int off = 1; off < 64; off <<= 1) sum += __shfl_xor(sum, off);
                float pv = e * 2.f / sum;
                if (half == 0) Pband[(bl * 2 + h) * NNBR + n2] = pv;
            }
            BARRIER();

            // ---- O = P @ V
            if (tid < 512) {
                int b = tid >> 7, c = tid & 127, h = c >> 6, d = c & 63;
                const float* P = Pband + (b * 2 + h) * NNBR;
                float s = 0.f;
                #pragma unroll
                for (int n2 = 0; n2 < NNBR; n2++) {
                    int np = h * 16 + (n2 >> 1);
                    int col = ODIM + (n2 & 1) * 64 + d;
                    s += P[n2] * bf2f(*(const unsigned short*)(smem + ZB(b * NNBR + np, col)));
                }
                Obuf[b * ODIM + c] = s;
            }
            BARRIER();

            // ---- out proj + LayerNorm
            {
                int b = (tid >> 7) & 3, c = tid & 127;
                float s = 0.f;
                if (tid < 512) {
                    s = bo[c];
                    const float* ob = Obuf + b * ODIM;
                    #pragma unroll 8
                    for (int k = 0; k < ODIM; k++)
                        s += ob[k] * bf2f(woT[k * 128 + c]);
                }
                float s1 = s, s2 = s * s;
                #pragma unroll
                for (int off = 1; off < 64; off <<= 1) {
                    s1 += __shfl_xor(s1, off);
                    s2 += __shfl_xor(s2, off);
                }
                if (tid < 512 && lane == 0) { red[wid * 2] = s1; red[wid * 2 + 1] = s2; }
                BARRIER();
                if (tid < 512) {
                    float t1 = red[b * 4 + 0] + red[b * 4 + 2];
                    float t2 = red[b * 4 + 1] + red[b * 4 + 3];
                    float mu  = t1 * (1.f / 128.f);
                    float var = t2 * (1.f / 128.f) - mu * mu;
                    float inv = rsqrtf(var + LN_EPS);
                    out[(long)(b0 + g * 4 + b) * ODIM + c] = (s - mu) * inv * gamma[c] + beta[c];
                }
            }
            BARRIER();   // tail done before next group's dumps reuse Z
        }
    }
}

extern "C" void kernel_launch(void* const* d_in, const int* in_sizes, int n_in,
                              void* d_out, int out_size, void* d_ws, size_t ws_size,
                              hipStream_t stream) {
    const float* node_feat = (const float*)d_in[0];
    const float* time_feat = (const float*)d_in[1];
    const float* edge_feat = (const float*)d_in[2];
    const float* nbr_node  = (const float*)d_in[3];
    const float* nbr_time  = (const float*)d_in[4];
    const int*   nbr_mask  = (const int*)d_in[5];
    const float* Wq   = (const float*)d_in[6];
    const float* bq   = (const float*)d_in[7];
    const float* Wkv  = (const float*)d_in[8];
    const float* bkv  = (const float*)d_in[9];
    const float* Wo   = (const float*)d_in[10];
    const float* bo   = (const float*)d_in[11];
    const float* gma  = (const float*)d_in[12];
    const float* bta  = (const float*)d_in[13];
    float* out = (float*)d_out;

    const int B = in_sizes[0] / NDIM;  // 8192

    // workspace layout
    char* ws = (char*)d_ws;
    float* Qbuf = (float*)ws;                                   // B*128*4 = 4 MB
    unsigned short* wfrag = (unsigned short*)(ws + (size_t)B * ODIM * 4);
    unsigned short* wqT   = wfrag + WFRAG_N;
    unsigned short* woT   = wqT + WQT_N;

    hipFuncSetAttribute((const void*)ta_fused,
                        hipFuncAttributeMaxDynamicSharedMemorySize, SMEM_BYTES);

    const int prep_total = WFRAG_N + WQT_N + WOT_N;
    prep_pack<<<dim3((prep_total + 255) / 256), dim3(256), 0, stream>>>(
        Wkv, Wq, Wo, wfrag, wqT, woT);
    q_proj<<<dim3(B / 8), dim3(256), 0, stream>>>(node_feat, time_feat, wqT, bq, Qbuf);
    ta_fused<<<dim3(B / RPB), dim3(1024), SMEM_BYTES, stream>>>(
        edge_feat, nbr_node, nbr_time, nbr_mask, Qbuf,
        wfrag, bkv, woT, bo, gma, bta, out);
}

// Round 16
// 209.345 us; speedup vs baseline: 2.4014x; 2.4014x over previous
//
#include <hip/hip_runtime.h>
#include <hip/hip_bf16.h>

typedef __attribute__((ext_vector_type(4))) float f32x4;
typedef __attribute__((ext_vector_type(8))) short short8;
typedef __attribute__((ext_vector_type(8))) __bf16 bf16x8;

#define NDIM 172
#define EDIM 172
#define TDIM 100
#define KCAT 444   // 172+172+100
#define QDIM 272   // 172+100
#define ODIM 128
#define ZDIM 256
#define NNBR 32
#define NPH 14     // K=32 phases (448 padded)
#define NT 7       // K=64 tiles
#define RPB 8      // batch rows per block
#define LN_EPS 1e-5f

// ---- LDS map (dynamic, ~96.8 KB, 1 block/CU) ----
// A slab double-buffered: 7 tiles x 4KB each = 28KB per buffer
#define A0_OFF   0
#define A1_OFF   28672
#define Z_OFF    57344     // Z bf16 [64][256] ZB-swizzled (2-batch-row groups)
#define QRES_OFF 90112     // [8][128] f32
#define MASK_OFF 94208     // [8][32] int
#define PB_OFF   95232     // [2][2][32] f32
#define OB_OFF   95744     // [2][128] f32
#define RED_OFF  96768     // [8][2] f32
#define SMEM_BYTES 96832

#define ZB(r,c) (Z_OFF + (((((r) * 512) + ((c) * 2)) ^ (((r) & 7) << 4))))

// lgkm-only barrier: vmcnt (the deep A-load pipeline) stays in flight
#define BARRIER() do { \
    asm volatile("s_waitcnt lgkmcnt(0)\ns_barrier" ::: "memory"); \
    __builtin_amdgcn_sched_barrier(0); \
} while (0)

__device__ __forceinline__ unsigned short f2bf(float f) {
    unsigned u = __builtin_bit_cast(unsigned, f);
    u += 0x7fffu + ((u >> 16) & 1u);
    return (unsigned short)(u >> 16);
}
__device__ __forceinline__ float bf2f(unsigned short h) {
    unsigned u = ((unsigned)h) << 16;
    return __builtin_bit_cast(float, u);
}
__device__ __forceinline__ unsigned short bfb(float f) {
    return __builtin_bit_cast(unsigned short, (__bf16)f);
}

// ---- prep: wfrag = Wkv bf16 in MFMA B-fragment order (R7 layout):
// [phase 0..13][n16 0..15][lane 0..63][8]; row=n16*16+(l&15), k=phase*32+(l>>4)*8+e
#define WFRAG_N (NPH * 8192)        // 114688 shorts
#define WQT_N (QDIM * ODIM)         // 34816
#define WOT_N (ODIM * ODIM)         // 16384
__global__ void prep_pack(const float* __restrict__ Wkv, const float* __restrict__ Wq,
                          const float* __restrict__ Wo,
                          unsigned short* __restrict__ wfrag,
                          unsigned short* __restrict__ wqT,
                          unsigned short* __restrict__ woT) {
    int idx = blockIdx.x * 256 + threadIdx.x;
    if (idx < WFRAG_N) {
        int phase = idx >> 13;
        int r = idx & 8191;
        int n16 = r >> 9;
        int q = r & 511;
        int l = q >> 3, e = q & 7;
        int row = n16 * 16 + (l & 15);
        int k = phase * 32 + ((l >> 4) << 3) + e;
        wfrag[idx] = f2bf(k < KCAT ? Wkv[row * KCAT + k] : 0.f);
    } else if (idx < WFRAG_N + WQT_N) {
        int j = idx - WFRAG_N;
        int k = j >> 7, c = j & 127;
        wqT[j] = f2bf(Wq[c * QDIM + k]);
    } else if (idx < WFRAG_N + WQT_N + WOT_N) {
        int j = idx - WFRAG_N - WQT_N;
        int k = j >> 7, c = j & 127;
        woT[j] = f2bf(Wo[c * ODIM + k]);
    }
}

// ---- Q projection (unchanged, proven)
__global__ __launch_bounds__(256) void q_proj(
    const float* __restrict__ node_feat, const float* __restrict__ time_feat,
    const unsigned short* __restrict__ wqT, const float* __restrict__ bq,
    float* __restrict__ Qbuf) {
    __shared__ float x[8][QDIM];
    const int tid = threadIdx.x;
    const long b0 = (long)blockIdx.x * 8;
    for (int g = tid; g < 8 * QDIM; g += 256) {
        int r = g / QDIM, k = g - r * QDIM;
        x[r][k] = (k < NDIM) ? node_feat[(b0 + r) * NDIM + k]
                             : time_feat[(b0 + r) * TDIM + (k - NDIM)];
    }
    __syncthreads();
    const int c = tid & 127;
    const int rb = (tid >> 7) * 4;
    float s0 = bq[c], s1 = s0, s2 = s0, s3 = s0;
    #pragma unroll 8
    for (int k = 0; k < QDIM; k++) {
        float w = bf2f(wqT[k * 128 + c]);
        s0 += x[rb + 0][k] * w;
        s1 += x[rb + 1][k] * w;
        s2 += x[rb + 2][k] * w;
        s3 += x[rb + 3][k] * w;
    }
    Qbuf[(b0 + rb + 0) * 128 + c] = s0;
    Qbuf[(b0 + rb + 1) * 128 + c] = s1;
    Qbuf[(b0 + rb + 2) * 128 + c] = s2;
    Qbuf[(b0 + rb + 3) * 128 + c] = s3;
}

// ---- fused: 512 thr / 8 waves (32-col bands). W in registers, PINNED
// against rematerialization via "+v" asm. A staged as a full 28KB slab per
// batch-row, double-buffered, ONE lgkm-barrier per row. (512,1): uncapped
// registers (~180 live) -> 2 waves/SIMD, no spill, no remat.
__global__ __launch_bounds__(512, 1) void ta_fused(
    const float* __restrict__ edge_feat, const float* __restrict__ nbr_node,
    const float* __restrict__ nbr_time, const int* __restrict__ nbr_mask,
    const float* __restrict__ Qbuf,
    const unsigned short* __restrict__ wfrag, const float* __restrict__ bkv,
    const unsigned short* __restrict__ woT, const float* __restrict__ bo,
    const float* __restrict__ gamma, const float* __restrict__ beta,
    float* __restrict__ out)
{
    extern __shared__ __align__(16) unsigned char smem[];
    float* qresL = (float*)(smem + QRES_OFF);
    int*   maskL = (int*)(smem + MASK_OFF);
    float* Pband = (float*)(smem + PB_OFF);
    float* Obuf  = (float*)(smem + OB_OFF);
    float* red   = (float*)(smem + RED_OFF);

    const int tid  = threadIdx.x;
    const int lane = tid & 63;
    const int wid  = tid >> 6;          // 0..7 = 32-col band
    const int b0   = blockIdx.x * RPB;

    // ---- stage masks + Q rows for the block's 8 batch rows
    if (tid < RPB * NNBR) maskL[tid] = nbr_mask[(long)b0 * NNBR + tid];
    qresL[tid]       = Qbuf[(long)b0 * ODIM + tid];
    qresL[tid + 512] = Qbuf[(long)b0 * ODIM + tid + 512];
    __syncthreads();   // one-time full drain, nothing deep in flight yet

    // ---- W fragments into registers, PINNED (cannot be rematerialized)
    short8 Wr[2 * NPH];
    #pragma unroll
    for (int p = 0; p < NPH; p++)
        #pragma unroll
        for (int j = 0; j < 2; j++)
            Wr[p * 2 + j] = *(const short8*)(wfrag +
                ((size_t)(p * 16 + wid * 2 + j) * 512 + lane * 8));
    #pragma unroll
    for (int i = 0; i < 2 * NPH; i++)
        asm volatile("" : "+v"(Wr[i]));   // anti-remat pin
    const float bk0 = bkv[wid * 32 + (lane & 15)];
    const float bk1 = bkv[wid * 32 + 16 + (lane & 15)];

    // ---- per-thread A geometry: thread = (rowA 0..31, kgrp 0..15)
    const int rowA  = tid >> 4;
    const int kgrp4 = (tid & 15) * 4;
    const int awb   = ((rowA * 128 + (tid & 15) * 8) ^ ((rowA & 7) << 4));

    auto loadA = [&](int riX, int t) -> float4 {
        int k = t * 64 + kgrp4;
        long rg = ((long)b0 + riX) * NNBR + rowA;
        const float* p; int off;
        if (k < NDIM)             { p = nbr_node  + rg * NDIM; off = k; }
        else if (k < NDIM + EDIM) { p = edge_feat + rg * EDIM; off = k - NDIM; }
        else { p = nbr_time + rg * TDIM; off = k - NDIM - EDIM;
               if (off > TDIM - 4) off = TDIM - 4; }   // pad: garbage x W=0
        return *(const float4*)(p + off);
    };
    auto writeSlab = [&](unsigned char* base, const float4* r4) {
        #pragma unroll
        for (int t = 0; t < NT; t++) {
            float4 v = r4[t];
            uint2 w;
            w.x = (unsigned)bfb(v.x) | ((unsigned)bfb(v.y) << 16);
            w.y = (unsigned)bfb(v.z) | ((unsigned)bfb(v.w) << 16);
            *(uint2*)(base + t * 4096 + awb) = w;
        }
    };

    // ---- prologue: slab0 = A(0); rs = A(1) in flight
    float4 rs[NT];
    #pragma unroll
    for (int t = 0; t < NT; t++) rs[t] = loadA(0, t);
    writeSlab(smem + A0_OFF, rs);        // waits the A(0) loads (one-time)
    #pragma unroll
    for (int t = 0; t < NT; t++) rs[t] = loadA(1, t);
    __builtin_amdgcn_sched_barrier(0);
    BARRIER();                            // slab0 visible; A(1) flying

    for (int ri = 0; ri < RPB; ri++) {
        unsigned char* slab = smem + ((ri & 1) ? A1_OFF : A0_OFF);
        unsigned char* slabN = smem + ((ri & 1) ? A0_OFF : A1_OFF);
        f32x4 acc[2][2];
        #pragma unroll
        for (int m = 0; m < 2; m++)
            #pragma unroll
            for (int n = 0; n < 2; n++) acc[m][n] = (f32x4){0.f, 0.f, 0.f, 0.f};

        // ---- compute: 56 MFMAs from slab (W from pinned registers)
        #pragma unroll
        for (int t = 0; t < NT; t++) {
            #pragma unroll
            for (int kk = 0; kk < 2; kk++) {
                bf16x8 af[2];
                #pragma unroll
                for (int m = 0; m < 2; m++) {
                    int row = m * 16 + (lane & 15);
                    af[m] = __builtin_bit_cast(bf16x8, *(const short8*)(
                        slab + t * 4096 + row * 128 +
                        ((kk * 64 + (lane >> 4) * 16) ^ ((row & 7) << 4))));
                }
                const int p = t * 2 + kk;
                acc[0][0] = __builtin_amdgcn_mfma_f32_16x16x32_bf16(af[0],
                    __builtin_bit_cast(bf16x8, Wr[p*2+0]), acc[0][0], 0, 0, 0);
                acc[0][1] = __builtin_amdgcn_mfma_f32_16x16x32_bf16(af[0],
                    __builtin_bit_cast(bf16x8, Wr[p*2+1]), acc[0][1], 0, 0, 0);
                acc[1][0] = __builtin_amdgcn_mfma_f32_16x16x32_bf16(af[1],
                    __builtin_bit_cast(bf16x8, Wr[p*2+0]), acc[1][0], 0, 0, 0);
                acc[1][1] = __builtin_amdgcn_mfma_f32_16x16x32_bf16(af[1],
                    __builtin_bit_cast(bf16x8, Wr[p*2+1]), acc[1][1], 0, 0, 0);
            }
        }

        // ---- write next slab (A(ri+1) landed during compute); refill A(ri+2)
        if (ri < RPB - 1) {
            writeSlab(slabN, rs);                     // counted vmcnt wait
            const int riN2 = (ri + 2 < RPB) ? ri + 2 : RPB - 1;
            #pragma unroll
            for (int t = 0; t < NT; t++) rs[t] = loadA(riN2, t);
            __builtin_amdgcn_sched_barrier(0);
        }

        // ---- dump Z row-block (+bkv); C/D: col=lane&15, row=(lane>>4)*4+j
        const int gi = ri & 1;               // 2-batch-row tail groups
        #pragma unroll
        for (int n = 0; n < 2; n++) {
            int col = wid * 32 + n * 16 + (lane & 15);
            float bk = n ? bk1 : bk0;
            #pragma unroll
            for (int m = 0; m < 2; m++)
                #pragma unroll
                for (int j = 0; j < 4; j++) {
                    int rowZ = gi * 32 + m * 16 + (lane >> 4) * 4 + j;
                    *(unsigned short*)(smem + ZB(rowZ, col)) = bfb(acc[m][n][j] + bk);
                }
        }
        BARRIER();   // slabN + Z dumps visible; A(ri+2) stays in flight

        if (gi == 1) {
            const int g = ri >> 1;             // tail group 0..3 (uniform)

            // ---- scores + softmax: waves 0..3 -> (bl=wid>>1, h=wid&1)
            if (wid < 4) {
                int bl = wid >> 1, h = wid & 1;
                int n2 = lane >> 1, half = lane & 1;
                int np = h * 16 + (n2 >> 1);
                int rowZ = bl * NNBR + np;
                int cb = (n2 & 1) * 64 + half * 32;
                const float* q = qresL + (g * 2 + bl) * ODIM + h * 64 + half * 32;
                float s = 0.f;
                #pragma unroll
                for (int j = 0; j < 4; j++) {
                    short8 z8 = *(const short8*)(smem + ZB(rowZ, cb + j * 8));
                    #pragma unroll
                    for (int e = 0; e < 8; e++)
                        s += q[j * 8 + e] * bf2f((unsigned short)z8[e]);
                }
                s += __shfl_xor(s, 1);
                s *= 0.125f;
                if (maskL[(g * 2 + bl) * NNBR + n2] == 0) s = -1e10f;
                float mx = s;
                #pragma unroll
                for (int off = 1; off < 64; off <<= 1) mx = fmaxf(mx, __shfl_xor(mx, off));
                float e = __expf(s - mx);
                float sum = e;
                #pragma unroll
                for (int off = 1; off < 64; off <<= 1) sum += __shfl_xor(sum, off);
                float pv = e * 2.f / sum;
                if (half == 0) Pband[(bl * 2 + h) * NNBR + n2] = pv;
            }
            BARRIER();

            // ---- O = P @ V  (2 rows x 128 cols = 256 threads)
            if (tid < 256) {
                int b = tid >> 7, c = tid & 127, h = c >> 6, d = c & 63;
                const float* P = Pband + (b * 2 + h) * NNBR;
                float s = 0.f;
                #pragma unroll
                for (int n2 = 0; n2 < NNBR; n2++) {
                    int np = h * 16 + (n2 >> 1);
                    int col = ODIM + (n2 & 1) * 64 + d;
                    s += P[n2] * bf2f(*(const unsigned short*)(smem + ZB(b * NNBR + np, col)));
                }
                Obuf[b * ODIM + c] = s;
            }
            BARRIER();

            // ---- out proj + LayerNorm (2 rows)
            {
                int b = (tid >> 7) & 1, c = tid & 127;
                float s = 0.f;
                if (tid < 256) {
                    s = bo[c];
                    const float* ob = Obuf + b * ODIM;
                    #pragma unroll 8
                    for (int k = 0; k < ODIM; k++)
                        s += ob[k] * bf2f(woT[k * 128 + c]);
                }
                float s1 = s, s2 = s * s;
                #pragma unroll
                for (int off = 1; off < 64; off <<= 1) {
                    s1 += __shfl_xor(s1, off);
                    s2 += __shfl_xor(s2, off);
                }
                if (tid < 256 && lane == 0) { red[wid * 2] = s1; red[wid * 2 + 1] = s2; }
                BARRIER();
                if (tid < 256) {
                    float t1 = red[b * 4 + 0] + red[b * 4 + 2];
                    float t2 = red[b * 4 + 1] + red[b * 4 + 3];
                    float mu  = t1 * (1.f / 128.f);
                    float var = t2 * (1.f / 128.f) - mu * mu;
                    float inv = rsqrtf(var + LN_EPS);
                    out[(long)(b0 + g * 2 + b) * ODIM + c] = (s - mu) * inv * gamma[c] + beta[c];
                }
            }
            BARRIER();   // tail done before next group's dumps reuse Z
        }
    }
}

extern "C" void kernel_launch(void* const* d_in, const int* in_sizes, int n_in,
                              void* d_out, int out_size, void* d_ws, size_t ws_size,
                              hipStream_t stream) {
    const float* node_feat = (const float*)d_in[0];
    const float* time_feat = (const float*)d_in[1];
    const float* edge_feat = (const float*)d_in[2];
    const float* nbr_node  = (const float*)d_in[3];
    const float* nbr_time  = (const float*)d_in[4];
    const int*   nbr_mask  = (const int*)d_in[5];
    const float* Wq   = (const float*)d_in[6];
    const float* bq   = (const float*)d_in[7];
    const float* Wkv  = (const float*)d_in[8];
    const float* bkv  = (const float*)d_in[9];
    const float* Wo   = (const float*)d_in[10];
    const float* bo   = (const float*)d_in[11];
    const float* gma  = (const float*)d_in[12];
    const float* bta  = (const float*)d_in[13];
    float* out = (float*)d_out;

    const int B = in_sizes[0] / NDIM;  // 8192

    // workspace layout
    char* ws = (char*)d_ws;
    float* Qbuf = (float*)ws;                                   // B*128*4 = 4 MB
    unsigned short* wfrag = (unsigned short*)(ws + (size_t)B * ODIM * 4);
    unsigned short* wqT   = wfrag + WFRAG_N;
    unsigned short* woT   = wqT + WQT_N;

    hipFuncSetAttribute((const void*)ta_fused,
                        hipFuncAttributeMaxDynamicSharedMemorySize, SMEM_BYTES);

    const int prep_total = WFRAG_N + WQT_N + WOT_N;
    prep_pack<<<dim3((prep_total + 255) / 256), dim3(256), 0, stream>>>(
        Wkv, Wq, Wo, wfrag, wqT, woT);
    q_proj<<<dim3(B / 8), dim3(256), 0, stream>>>(node_feat, time_feat, wqT, bq, Qbuf);
    ta_fused<<<dim3(B / RPB), dim3(512), SMEM_BYTES, stream>>>(
        edge_feat, nbr_node, nbr_time, nbr_mask, Qbuf,
        wfrag, bkv, woT, bo, gma, bta, out);
}

// Round 17
// 184.207 us; speedup vs baseline: 2.7291x; 1.1365x over previous
//
#include <hip/hip_runtime.h>
#include <hip/hip_bf16.h>

typedef __attribute__((ext_vector_type(4))) float f32x4;
typedef __attribute__((ext_vector_type(8))) short short8;
typedef __attribute__((ext_vector_type(8))) __bf16 bf16x8;

#define NDIM 172
#define EDIM 172
#define TDIM 100
#define KCAT 444   // 172+172+100
#define QDIM 272   // 172+100
#define ODIM 128
#define ZDIM 256
#define NNBR 32
#define NPH 14     // K=32 phases (448 padded)
#define NT 7       // K=64 tiles
#define RPB 8      // batch rows per block
#define LN_EPS 1e-5f

// ---- LDS map (dynamic, ~80 KB, 1 block/CU) ----
#define Z_OFF    0         // Z bf16 [128][256] ZB-swizzled (4-row tail groups)
#define A_OFF    65536     // A exchange: 2 slots x 4 KB bf16 [32][64] swizzled
#define QRES_OFF 73728     // [8][128] f32
#define MASK_OFF 77824     // [8][32] int
#define PB_OFF   78848     // [4][2][32] f32
#define OB_OFF   79872     // [4][128] f32
#define RED_OFF  81920     // [8][2] f32
#define SMEM_BYTES 81984

#define ZB(r,c) ((((r) * 512) + ((c) * 2)) ^ (((r) & 7) << 4))

// lgkm-only barrier: vmcnt (the deep A-load pipeline) stays in flight
#define BARRIER() do { \
    asm volatile("s_waitcnt lgkmcnt(0)\ns_barrier" ::: "memory"); \
    __builtin_amdgcn_sched_barrier(0); \
} while (0)

__device__ __forceinline__ unsigned short f2bf(float f) {
    unsigned u = __builtin_bit_cast(unsigned, f);
    u += 0x7fffu + ((u >> 16) & 1u);
    return (unsigned short)(u >> 16);
}
__device__ __forceinline__ float bf2f(unsigned short h) {
    unsigned u = ((unsigned)h) << 16;
    return __builtin_bit_cast(float, u);
}
__device__ __forceinline__ unsigned short bfb(float f) {
    return __builtin_bit_cast(unsigned short, (__bf16)f);
}

// ---- prep: wfrag = Wkv bf16 in MFMA B-fragment order (R7 layout):
// [phase 0..13][n16 0..15][lane 0..63][8]; row=n16*16+(l&15), k=phase*32+(l>>4)*8+e
#define WFRAG_N (NPH * 8192)        // 114688 shorts
#define WQT_N (QDIM * ODIM)         // 34816
#define WOT_N (ODIM * ODIM)         // 16384
__global__ void prep_pack(const float* __restrict__ Wkv, const float* __restrict__ Wq,
                          const float* __restrict__ Wo,
                          unsigned short* __restrict__ wfrag,
                          unsigned short* __restrict__ wqT,
                          unsigned short* __restrict__ woT) {
    int idx = blockIdx.x * 256 + threadIdx.x;
    if (idx < WFRAG_N) {
        int phase = idx >> 13;
        int r = idx & 8191;
        int n16 = r >> 9;
        int q = r & 511;
        int l = q >> 3, e = q & 7;
        int row = n16 * 16 + (l & 15);
        int k = phase * 32 + ((l >> 4) << 3) + e;
        wfrag[idx] = f2bf(k < KCAT ? Wkv[row * KCAT + k] : 0.f);
    } else if (idx < WFRAG_N + WQT_N) {
        int j = idx - WFRAG_N;
        int k = j >> 7, c = j & 127;
        wqT[j] = f2bf(Wq[c * QDIM + k]);
    } else if (idx < WFRAG_N + WQT_N + WOT_N) {
        int j = idx - WFRAG_N - WQT_N;
        int k = j >> 7, c = j & 127;
        woT[j] = f2bf(Wo[c * ODIM + k]);
    }
}

// ---- Q projection (unchanged, proven)
__global__ __launch_bounds__(256) void q_proj(
    const float* __restrict__ node_feat, const float* __restrict__ time_feat,
    const unsigned short* __restrict__ wqT, const float* __restrict__ bq,
    float* __restrict__ Qbuf) {
    __shared__ float x[8][QDIM];
    const int tid = threadIdx.x;
    const long b0 = (long)blockIdx.x * 8;
    for (int g = tid; g < 8 * QDIM; g += 256) {
        int r = g / QDIM, k = g - r * QDIM;
        x[r][k] = (k < NDIM) ? node_feat[(b0 + r) * NDIM + k]
                             : time_feat[(b0 + r) * TDIM + (k - NDIM)];
    }
    __syncthreads();
    const int c = tid & 127;
    const int rb = (tid >> 7) * 4;
    float s0 = bq[c], s1 = s0, s2 = s0, s3 = s0;
    #pragma unroll 8
    for (int k = 0; k < QDIM; k++) {
        float w = bf2f(wqT[k * 128 + c]);
        s0 += x[rb + 0][k] * w;
        s1 += x[rb + 1][k] * w;
        s2 += x[rb + 2][k] * w;
        s3 += x[rb + 3][k] * w;
    }
    Qbuf[(b0 + rb + 0) * 128 + c] = s0;
    Qbuf[(b0 + rb + 1) * 128 + c] = s1;
    Qbuf[(b0 + rb + 2) * 128 + c] = s2;
    Qbuf[(b0 + rb + 3) * 128 + c] = s3;
}

// ---- fused (R12 structure): W in registers, A reg-pipelined 7 tiles deep,
// tiny LDS exchange, lgkm-only barriers. NEW: branch-free A addressing via
// per-thread pointer/stride tables; slot parity (t+ri)&1; setprio on MFMAs.
__global__ __launch_bounds__(512, 2) void ta_fused(
    const float* __restrict__ edge_feat, const float* __restrict__ nbr_node,
    const float* __restrict__ nbr_time, const int* __restrict__ nbr_mask,
    const float* __restrict__ Qbuf,
    const unsigned short* __restrict__ wfrag, const float* __restrict__ bkv,
    const unsigned short* __restrict__ woT, const float* __restrict__ bo,
    const float* __restrict__ gamma, const float* __restrict__ beta,
    float* __restrict__ out)
{
    extern __shared__ __align__(16) unsigned char smem[];
    float* qresL = (float*)(smem + QRES_OFF);
    int*   maskL = (int*)(smem + MASK_OFF);
    float* Pband = (float*)(smem + PB_OFF);
    float* Obuf  = (float*)(smem + OB_OFF);
    float* red   = (float*)(smem + RED_OFF);

    const int tid  = threadIdx.x;
    const int lane = tid & 63;
    const int wid  = tid >> 6;          // 0..7 = 32-col band
    const int b0   = blockIdx.x * RPB;

    // ---- stage masks + Q rows for the block's 8 batch rows
    if (tid < RPB * NNBR) maskL[tid] = nbr_mask[(long)b0 * NNBR + tid];
    qresL[tid]       = Qbuf[(long)b0 * ODIM + tid];
    qresL[tid + 512] = Qbuf[(long)b0 * ODIM + tid + 512];
    __syncthreads();   // one-time full drain, nothing deep in flight yet

    // ---- W fragments into registers (read-only, literal indices only)
    bf16x8 Wr[2 * NPH];
    #pragma unroll
    for (int p = 0; p < NPH; p++)
        #pragma unroll
        for (int j = 0; j < 2; j++)
            Wr[p * 2 + j] = __builtin_bit_cast(bf16x8,
                *(const short8*)(wfrag + ((size_t)(p * 16 + wid * 2 + j) * 512 + lane * 8)));
    const float bk0 = bkv[wid * 32 + (lane & 15)];
    const float bk1 = bkv[wid * 32 + 16 + (lane & 15)];

    // ---- per-thread A geometry: thread = (rowA 0..31, kgrp 0..15)
    const int rowA  = tid >> 4;
    const int kgrp4 = (tid & 15) * 4;
    const int awb   = ((rowA * 128 + (tid & 15) * 8) ^ ((rowA & 7) << 4));

    // Branch-free A addressing: tensor choice per (thread, tile) is STATIC.
    // Resolve once into pointer + stride tables; steady-state refill is one
    // dwordx4 load + one 64-bit add per tile.
    const float* aptr[NT];
    int astr[NT];
    #pragma unroll
    for (int t = 0; t < NT; t++) {
        int k = t * 64 + kgrp4;
        long rg = (long)b0 * NNBR + rowA;
        if (k < NDIM) {
            aptr[t] = nbr_node + rg * NDIM + k;
            astr[t] = NNBR * NDIM;
        } else if (k < NDIM + EDIM) {
            aptr[t] = edge_feat + rg * EDIM + (k - NDIM);
            astr[t] = NNBR * EDIM;
        } else {
            int off = k - NDIM - EDIM;
            if (off > TDIM - 4) off = TDIM - 4;   // pad: garbage x W=0
            aptr[t] = nbr_time + rg * TDIM + off;
            astr[t] = NNBR * TDIM;
        }
    }

    // ---- prologue: iteration 0's 7 tiles in flight (the latency buffer)
    float4 rs[NT];
    #pragma unroll
    for (int t = 0; t < NT; t++) {
        rs[t] = *(const float4*)aptr[t];
        aptr[t] += astr[t];
    }
    __builtin_amdgcn_sched_barrier(0);

    for (int ri = 0; ri < RPB; ri++) {
        const int sp = ri & 1;          // slot parity alternates across ri
        f32x4 acc[2][2];
        #pragma unroll
        for (int m = 0; m < 2; m++)
            #pragma unroll
            for (int n = 0; n < 2; n++) acc[m][n] = (f32x4){0.f, 0.f, 0.f, 0.f};

        #pragma unroll
        for (int t = 0; t < NT; t++) {
            unsigned char* aw = smem + A_OFF + (((t + sp) & 1) ? 4096 : 0);
            // stage tile (ri,t): loaded 7 tiles ago -> counted vmcnt wait
            {
                float4 v = rs[t];
                uint2 w;
                w.x = (unsigned)bfb(v.x) | ((unsigned)bfb(v.y) << 16);
                w.y = (unsigned)bfb(v.z) | ((unsigned)bfb(v.w) << 16);
                *(uint2*)(aw + awb) = w;
            }
            if (ri + 1 < RPB) {               // refill: iter ri+1, same tile
                rs[t] = *(const float4*)aptr[t];
                aptr[t] += astr[t];
            }
            __builtin_amdgcn_sched_barrier(0);
            BARRIER();                         // exchange visible; vmem in flight
            // compute tile t: phases 2t, 2t+1 (W from registers)
            __builtin_amdgcn_s_setprio(1);
            #pragma unroll
            for (int kk = 0; kk < 2; kk++) {
                bf16x8 af[2];
                #pragma unroll
                for (int m = 0; m < 2; m++) {
                    int row = m * 16 + (lane & 15);
                    af[m] = __builtin_bit_cast(bf16x8, *(const short8*)(
                        aw + row * 128 + ((kk * 64 + (lane >> 4) * 16) ^ ((row & 7) << 4))));
                }
                const int p = t * 2 + kk;
                acc[0][0] = __builtin_amdgcn_mfma_f32_16x16x32_bf16(af[0], Wr[p*2+0], acc[0][0], 0, 0, 0);
                acc[0][1] = __builtin_amdgcn_mfma_f32_16x16x32_bf16(af[0], Wr[p*2+1], acc[0][1], 0, 0, 0);
                acc[1][0] = __builtin_amdgcn_mfma_f32_16x16x32_bf16(af[1], Wr[p*2+0], acc[1][0], 0, 0, 0);
                acc[1][1] = __builtin_amdgcn_mfma_f32_16x16x32_bf16(af[1], Wr[p*2+1], acc[1][1], 0, 0, 0);
            }
            __builtin_amdgcn_s_setprio(0);
        }

        // ---- dump Z row-block (+bkv); C/D: col=lane&15, row=(lane>>4)*4+j
        const int gi = ri & 3;
        #pragma unroll
        for (int n = 0; n < 2; n++) {
            int col = wid * 32 + n * 16 + (lane & 15);
            float bk = n ? bk1 : bk0;
            #pragma unroll
            for (int m = 0; m < 2; m++)
                #pragma unroll
                for (int j = 0; j < 4; j++) {
                    int rowZ = gi * 32 + m * 16 + (lane >> 4) * 4 + j;
                    *(unsigned short*)(smem + ZB(rowZ, col)) = bfb(acc[m][n][j] + bk);
                }
        }

        if (gi == 3) {
            const int g = ri >> 2;             // tail group 0/1 (uniform)
            BARRIER();                          // dumps visible; A loads keep flying

            // ---- scores + softmax: waves 0..7 -> (bl=wid>>1, h=wid&1)
            {
                int bl = wid >> 1, h = wid & 1;
                int n2 = lane >> 1, half = lane & 1;
                int np = h * 16 + (n2 >> 1);
                int rowZ = bl * NNBR + np;
                int cb = (n2 & 1) * 64 + half * 32;
                const float* q = qresL + (g * 4 + bl) * ODIM + h * 64 + half * 32;
                float s = 0.f;
                #pragma unroll
                for (int j = 0; j < 4; j++) {
                    short8 z8 = *(const short8*)(smem + ZB(rowZ, cb + j * 8));
                    #pragma unroll
                    for (int e = 0; e < 8; e++)
                        s += q[j * 8 + e] * bf2f((unsigned short)z8[e]);
                }
                s += __shfl_xor(s, 1);
                s *= 0.125f;
                if (maskL[(g * 4 + bl) * NNBR + n2] == 0) s = -1e10f;
                float mx = s;
                #pragma unroll
                for (int off = 1; off < 64; off <<= 1) mx = fmaxf(mx, __shfl_xor(mx, off));
                float e = __expf(s - mx);
                float sum = e;
                #pragma unroll
                for (int off = 1; off < 64; off <<= 1) sum += __shfl_xor(sum, off);
                float pv = e * 2.f / sum;
                if (half == 0) Pband[(bl * 2 + h) * NNBR + n2] = pv;
            }
            BARRIER();

            // ---- O = P @ V
            {
                int b = tid >> 7, c = tid & 127, h = c >> 6, d = c & 63;
                const float* P = Pband + (b * 2 + h) * NNBR;
                float s = 0.f;
                #pragma unroll
                for (int n2 = 0; n2 < NNBR; n2++) {
                    int np = h * 16 + (n2 >> 1);
                    int col = ODIM + (n2 & 1) * 64 + d;
                    s += P[n2] * bf2f(*(const unsigned short*)(smem + ZB(b * NNBR + np, col)));
                }
                Obuf[b * ODIM + c] = s;
            }
            BARRIER();

            // ---- out proj + LayerNorm
            {
                int b = tid >> 7, c = tid & 127;
                float s = bo[c];
                const float* ob = Obuf + b * ODIM;
                #pragma unroll 8
                for (int k = 0; k < ODIM; k++)
                    s += ob[k] * bf2f(woT[k * 128 + c]);
                float s1 = s, s2 = s * s;
                #pragma unroll
                for (int off = 1; off < 64; off <<= 1) {
                    s1 += __shfl_xor(s1, off);
                    s2 += __shfl_xor(s2, off);
                }
                if (lane == 0) { red[wid * 2] = s1; red[wid * 2 + 1] = s2; }
                BARRIER();
                float t1 = red[b * 4 + 0] + red[b * 4 + 2];
                float t2 = red[b * 4 + 1] + red[b * 4 + 3];
                float mu  = t1 * (1.f / 128.f);
                float var = t2 * (1.f / 128.f) - mu * mu;
                float inv = rsqrtf(var + LN_EPS);
                out[(long)(b0 + g * 4 + b) * ODIM + c] = (s - mu) * inv * gamma[c] + beta[c];
            }
            BARRIER();   // tail done before next group's dumps reuse Z
        }
    }
}

extern "C" void kernel_launch(void* const* d_in, const int* in_sizes, int n_in,
                              void* d_out, int out_size, void* d_ws, size_t ws_size,
                              hipStream_t stream) {
    const float* node_feat = (const float*)d_in[0];
    const float* time_feat = (const float*)d_in[1];
    const float* edge_feat = (const float*)d_in[2];
    const float* nbr_node  = (const float*)d_in[3];
    const float* nbr_time  = (const float*)d_in[4];
    const int*   nbr_mask  = (const int*)d_in[5];
    const float* Wq   = (const float*)d_in[6];
    const float* bq   = (const float*)d_in[7];
    const float* Wkv  = (const float*)d_in[8];
    const float* bkv  = (const float*)d_in[9];
    const float* Wo   = (const float*)d_in[10];
    const float* bo   = (const float*)d_in[11];
    const float* gma  = (const float*)d_in[12];
    const float* bta  = (const float*)d_in[13];
    float* out = (float*)d_out;

    const int B = in_sizes[0] / NDIM;  // 8192

    // workspace layout
    char* ws = (char*)d_ws;
    float* Qbuf = (float*)ws;                                   // B*128*4 = 4 MB
    unsigned short* wfrag = (unsigned short*)(ws + (size_t)B * ODIM * 4);
    unsigned short* wqT   = wfrag + WFRAG_N;
    unsigned short* woT   = wqT + WQT_N;

    hipFuncSetAttribute((const void*)ta_fused,
                        hipFuncAttributeMaxDynamicSharedMemorySize, SMEM_BYTES);

    const int prep_total = WFRAG_N + WQT_N + WOT_N;
    prep_pack<<<dim3((prep_total + 255) / 256), dim3(256), 0, stream>>>(
        Wkv, Wq, Wo, wfrag, wqT, woT);
    q_proj<<<dim3(B / 8), dim3(256), 0, stream>>>(node_feat, time_feat, wqT, bq, Qbuf);
    ta_fused<<<dim3(B / RPB), dim3(512), SMEM_BYTES, stream>>>(
        edge_feat, nbr_node, nbr_time, nbr_mask, Qbuf,
        wfrag, bkv, woT, bo, gma, bta, out);
}

// Round 18
// 173.549 us; speedup vs baseline: 2.8967x; 1.0614x over previous
//
#include <hip/hip_runtime.h>
#include <hip/hip_bf16.h>

typedef __attribute__((ext_vector_type(4))) float f32x4;
typedef __attribute__((ext_vector_type(8))) short short8;
typedef __attribute__((ext_vector_type(8))) __bf16 bf16x8;

#define NDIM 172
#define EDIM 172
#define TDIM 100
#define KCAT 444   // 172+172+100
#define QDIM 272   // 172+100
#define ODIM 128
#define ZDIM 256
#define NNBR 32
#define NPH 14     // K=32 phases (448 padded)
#define NT 7       // K=64 tiles
#define RPB 32     // batch rows per block -> grid = 256 = 1 block/CU, persistent
#define LN_EPS 1e-5f

// ---- LDS map (dynamic, ~105.6 KB, 1 block/CU by design) ----
#define Z_OFF    0         // Z bf16 [128][256] ZB-swizzled (4-row tail groups)
#define A_OFF    65536     // A exchange: 4 slots x 4 KB bf16 [32][64] swizzled
#define QRES_OFF 81920     // [32][128] f32
#define MASK_OFF 98304     // [32][32] int
#define PB_OFF   102400    // [4][2][32] f32
#define OB_OFF   103424    // [4][128] f32
#define RED_OFF  105472    // [16][2] f32
#define SMEM_BYTES 105600

#define ZB(r,c) ((((r) * 512) + ((c) * 2)) ^ (((r) & 7) << 4))

// lgkm-only barrier: vmcnt (the deep A-load pipeline) stays in flight
#define BARRIER() do { \
    asm volatile("s_waitcnt lgkmcnt(0)\ns_barrier" ::: "memory"); \
    __builtin_amdgcn_sched_barrier(0); \
} while (0)

__device__ __forceinline__ unsigned short f2bf(float f) {
    unsigned u = __builtin_bit_cast(unsigned, f);
    u += 0x7fffu + ((u >> 16) & 1u);
    return (unsigned short)(u >> 16);
}
__device__ __forceinline__ float bf2f(unsigned short h) {
    unsigned u = ((unsigned)h) << 16;
    return __builtin_bit_cast(float, u);
}
__device__ __forceinline__ unsigned short bfb(float f) {
    return __builtin_bit_cast(unsigned short, (__bf16)f);
}

// ---- prep: wfrag = Wkv bf16 in MFMA B-fragment order (R7 layout):
// [phase 0..13][n16 0..15][lane 0..63][8]; row=n16*16+(l&15), k=phase*32+(l>>4)*8+e
#define WFRAG_N (NPH * 8192)        // 114688 shorts
#define WQT_N (QDIM * ODIM)         // 34816
#define WOT_N (ODIM * ODIM)         // 16384
__global__ void prep_pack(const float* __restrict__ Wkv, const float* __restrict__ Wq,
                          const float* __restrict__ Wo,
                          unsigned short* __restrict__ wfrag,
                          unsigned short* __restrict__ wqT,
                          unsigned short* __restrict__ woT) {
    int idx = blockIdx.x * 256 + threadIdx.x;
    if (idx < WFRAG_N) {
        int phase = idx >> 13;
        int r = idx & 8191;
        int n16 = r >> 9;
        int q = r & 511;
        int l = q >> 3, e = q & 7;
        int row = n16 * 16 + (l & 15);
        int k = phase * 32 + ((l >> 4) << 3) + e;
        wfrag[idx] = f2bf(k < KCAT ? Wkv[row * KCAT + k] : 0.f);
    } else if (idx < WFRAG_N + WQT_N) {
        int j = idx - WFRAG_N;
        int k = j >> 7, c = j & 127;
        wqT[j] = f2bf(Wq[c * QDIM + k]);
    } else if (idx < WFRAG_N + WQT_N + WOT_N) {
        int j = idx - WFRAG_N - WQT_N;
        int k = j >> 7, c = j & 127;
        woT[j] = f2bf(Wo[c * ODIM + k]);
    }
}

// ---- Q projection (unchanged, proven)
__global__ __launch_bounds__(256) void q_proj(
    const float* __restrict__ node_feat, const float* __restrict__ time_feat,
    const unsigned short* __restrict__ wqT, const float* __restrict__ bq,
    float* __restrict__ Qbuf) {
    __shared__ float x[8][QDIM];
    const int tid = threadIdx.x;
    const long b0 = (long)blockIdx.x * 8;
    for (int g = tid; g < 8 * QDIM; g += 256) {
        int r = g / QDIM, k = g - r * QDIM;
        x[r][k] = (k < NDIM) ? node_feat[(b0 + r) * NDIM + k]
                             : time_feat[(b0 + r) * TDIM + (k - NDIM)];
    }
    __syncthreads();
    const int c = tid & 127;
    const int rb = (tid >> 7) * 4;
    float s0 = bq[c], s1 = s0, s2 = s0, s3 = s0;
    #pragma unroll 8
    for (int k = 0; k < QDIM; k++) {
        float w = bf2f(wqT[k * 128 + c]);
        s0 += x[rb + 0][k] * w;
        s1 += x[rb + 1][k] * w;
        s2 += x[rb + 2][k] * w;
        s3 += x[rb + 3][k] * w;
    }
    Qbuf[(b0 + rb + 0) * 128 + c] = s0;
    Qbuf[(b0 + rb + 1) * 128 + c] = s1;
    Qbuf[(b0 + rb + 2) * 128 + c] = s2;
    Qbuf[(b0 + rb + 3) * 128 + c] = s3;
}

// ---- fused (R12/R17 hot path): W in registers, A reg-pipelined 7 deep.
// NEW: persistent blocks (RPB=32, grid=256) + 2 tiles per barrier window
// (4 windows/ri over 4 rotating slots; rolling refill preserved).
__global__ __launch_bounds__(512, 2) void ta_fused(
    const float* __restrict__ edge_feat, const float* __restrict__ nbr_node,
    const float* __restrict__ nbr_time, const int* __restrict__ nbr_mask,
    const float* __restrict__ Qbuf,
    const unsigned short* __restrict__ wfrag, const float* __restrict__ bkv,
    const unsigned short* __restrict__ woT, const float* __restrict__ bo,
    const float* __restrict__ gamma, const float* __restrict__ beta,
    float* __restrict__ out)
{
    extern __shared__ __align__(16) unsigned char smem[];
    float* qresL = (float*)(smem + QRES_OFF);
    int*   maskL = (int*)(smem + MASK_OFF);
    float* Pband = (float*)(smem + PB_OFF);
    float* Obuf  = (float*)(smem + OB_OFF);
    float* red   = (float*)(smem + RED_OFF);

    const int tid  = threadIdx.x;
    const int lane = tid & 63;
    const int wid  = tid >> 6;          // 0..7 = 32-col band
    const int b0   = blockIdx.x * RPB;

    // ---- stage masks + Q rows for the block's 32 batch rows (one-time)
    for (int i = tid; i < RPB * NNBR; i += 512)
        maskL[i] = nbr_mask[(long)b0 * NNBR + i];
    for (int i = tid; i < RPB * ODIM; i += 512)
        qresL[i] = Qbuf[(long)b0 * ODIM + i];
    __syncthreads();   // one-time full drain, nothing deep in flight yet

    // ---- W fragments into registers (one-time; read-only, literal indices)
    bf16x8 Wr[2 * NPH];
    #pragma unroll
    for (int p = 0; p < NPH; p++)
        #pragma unroll
        for (int j = 0; j < 2; j++)
            Wr[p * 2 + j] = __builtin_bit_cast(bf16x8,
                *(const short8*)(wfrag + ((size_t)(p * 16 + wid * 2 + j) * 512 + lane * 8)));
    const float bk0 = bkv[wid * 32 + (lane & 15)];
    const float bk1 = bkv[wid * 32 + 16 + (lane & 15)];

    // ---- per-thread A geometry: thread = (rowA 0..31, kgrp 0..15)
    const int rowA  = tid >> 4;
    const int kgrp4 = (tid & 15) * 4;
    const int awb   = ((rowA * 128 + (tid & 15) * 8) ^ ((rowA & 7) << 4));

    // Branch-free A addressing: per-thread pointer + stride tables
    const float* aptr[NT];
    int astr[NT];
    #pragma unroll
    for (int t = 0; t < NT; t++) {
        int k = t * 64 + kgrp4;
        long rg = (long)b0 * NNBR + rowA;
        if (k < NDIM) {
            aptr[t] = nbr_node + rg * NDIM + k;
            astr[t] = NNBR * NDIM;
        } else if (k < NDIM + EDIM) {
            aptr[t] = edge_feat + rg * EDIM + (k - NDIM);
            astr[t] = NNBR * EDIM;
        } else {
            int off = k - NDIM - EDIM;
            if (off > TDIM - 4) off = TDIM - 4;   // pad: garbage x W=0
            aptr[t] = nbr_time + rg * TDIM + off;
            astr[t] = NNBR * TDIM;
        }
    }

    // ---- prologue: iteration 0's 7 tiles in flight (the latency buffer)
    float4 rs[NT];
    #pragma unroll
    for (int t = 0; t < NT; t++) {
        rs[t] = *(const float4*)aptr[t];
        aptr[t] += astr[t];
    }
    __builtin_amdgcn_sched_barrier(0);

    for (int ri = 0; ri < RPB; ri++) {
        const int tb = ri * NT;         // rolling slot counter base
        f32x4 acc[2][2];
        #pragma unroll
        for (int m = 0; m < 2; m++)
            #pragma unroll
            for (int n = 0; n < 2; n++) acc[m][n] = (f32x4){0.f, 0.f, 0.f, 0.f};

        #pragma unroll
        for (int w = 0; w < 4; w++) {   // windows {0,1}{2,3}{4,5}{6}
            const int t0 = w * 2;
            unsigned char* aw0 = smem + A_OFF + (((tb + t0) & 3) << 12);
            unsigned char* aw1 = smem + A_OFF + (((tb + t0 + 1) & 3) << 12);
            // stage window's tiles (loads issued ~7 windows ago -> counted wait)
            {
                float4 v = rs[t0];
                uint2 u;
                u.x = (unsigned)bfb(v.x) | ((unsigned)bfb(v.y) << 16);
                u.y = (unsigned)bfb(v.z) | ((unsigned)bfb(v.w) << 16);
                *(uint2*)(aw0 + awb) = u;
            }
            if (t0 + 1 < NT) {
                float4 v = rs[t0 + 1];
                uint2 u;
                u.x = (unsigned)bfb(v.x) | ((unsigned)bfb(v.y) << 16);
                u.y = (unsigned)bfb(v.z) | ((unsigned)bfb(v.w) << 16);
                *(uint2*)(aw1 + awb) = u;
            }
            // rolling refill: iter ri+1, same tiles
            if (ri + 1 < RPB) {
                rs[t0] = *(const float4*)aptr[t0];
                aptr[t0] += astr[t0];
                if (t0 + 1 < NT) {
                    rs[t0 + 1] = *(const float4*)aptr[t0 + 1];
                    aptr[t0 + 1] += astr[t0 + 1];
                }
            }
            __builtin_amdgcn_sched_barrier(0);
            BARRIER();                   // exchange visible; vmem stays in flight
            // compute window (W from registers)
            __builtin_amdgcn_s_setprio(1);
            #pragma unroll
            for (int tt = 0; tt < 2; tt++) {
                if (t0 + tt < NT) {
                    const unsigned char* aw = tt ? aw1 : aw0;
                    #pragma unroll
                    for (int kk = 0; kk < 2; kk++) {
                        bf16x8 af[2];
                        #pragma unroll
                        for (int m = 0; m < 2; m++) {
                            int row = m * 16 + (lane & 15);
                            af[m] = __builtin_bit_cast(bf16x8, *(const short8*)(
                                aw + row * 128 + ((kk * 64 + (lane >> 4) * 16) ^ ((row & 7) << 4))));
                        }
                        const int p = (t0 + tt) * 2 + kk;
                        acc[0][0] = __builtin_amdgcn_mfma_f32_16x16x32_bf16(af[0], Wr[p*2+0], acc[0][0], 0, 0, 0);
                        acc[0][1] = __builtin_amdgcn_mfma_f32_16x16x32_bf16(af[0], Wr[p*2+1], acc[0][1], 0, 0, 0);
                        acc[1][0] = __builtin_amdgcn_mfma_f32_16x16x32_bf16(af[1], Wr[p*2+0], acc[1][0], 0, 0, 0);
                        acc[1][1] = __builtin_amdgcn_mfma_f32_16x16x32_bf16(af[1], Wr[p*2+1], acc[1][1], 0, 0, 0);
                    }
                }
            }
            __builtin_amdgcn_s_setprio(0);
        }

        // ---- dump Z row-block (+bkv); C/D: col=lane&15, row=(lane>>4)*4+j
        const int gi = ri & 3;
        #pragma unroll
        for (int n = 0; n < 2; n++) {
            int col = wid * 32 + n * 16 + (lane & 15);
            float bk = n ? bk1 : bk0;
            #pragma unroll
            for (int m = 0; m < 2; m++)
                #pragma unroll
                for (int j = 0; j < 4; j++) {
                    int rowZ = gi * 32 + m * 16 + (lane >> 4) * 4 + j;
                    *(unsigned short*)(smem + ZB(rowZ, col)) = bfb(acc[m][n][j] + bk);
                }
        }

        if (gi == 3) {
            const int g = ri >> 2;             // tail group 0..7 (uniform)
            BARRIER();                          // dumps visible; A loads keep flying

            // ---- scores + softmax: waves 0..7 -> (bl=wid>>1, h=wid&1)
            {
                int bl = wid >> 1, h = wid & 1;
                int n2 = lane >> 1, half = lane & 1;
                int np = h * 16 + (n2 >> 1);
                int rowZ = bl * NNBR + np;
                int cb = (n2 & 1) * 64 + half * 32;
                const float* q = qresL + (g * 4 + bl) * ODIM + h * 64 + half * 32;
                float s = 0.f;
                #pragma unroll
                for (int j = 0; j < 4; j++) {
                    short8 z8 = *(const short8*)(smem + ZB(rowZ, cb + j * 8));
                    #pragma unroll
                    for (int e = 0; e < 8; e++)
                        s += q[j * 8 + e] * bf2f((unsigned short)z8[e]);
                }
                s += __shfl_xor(s, 1);
                s *= 0.125f;
                if (maskL[(g * 4 + bl) * NNBR + n2] == 0) s = -1e10f;
                float mx = s;
                #pragma unroll
                for (int off = 1; off < 64; off <<= 1) mx = fmaxf(mx, __shfl_xor(mx, off));
                float e = __expf(s - mx);
                float sum = e;
                #pragma unroll
                for (int off = 1; off < 64; off <<= 1) sum += __shfl_xor(sum, off);
                float pv = e * 2.f / sum;
                if (half == 0) Pband[(bl * 2 + h) * NNBR + n2] = pv;
            }
            BARRIER();

            // ---- O = P @ V
            {
                int b = tid >> 7, c = tid & 127, h = c >> 6, d = c & 63;
                const float* P = Pband + (b * 2 + h) * NNBR;
                float s = 0.f;
                #pragma unroll
                for (int n2 = 0; n2 < NNBR; n2++) {
                    int np = h * 16 + (n2 >> 1);
                    int col = ODIM + (n2 & 1) * 64 + d;
                    s += P[n2] * bf2f(*(const unsigned short*)(smem + ZB(b * NNBR + np, col)));
                }
                Obuf[b * ODIM + c] = s;
            }
            BARRIER();

            // ---- out proj + LayerNorm
            {
                int b = tid >> 7, c = tid & 127;
                float s = bo[c];
                const float* ob = Obuf + b * ODIM;
                #pragma unroll 8
                for (int k = 0; k < ODIM; k++)
                    s += ob[k] * bf2f(woT[k * 128 + c]);
                float s1 = s, s2 = s * s;
                #pragma unroll
                for (int off = 1; off < 64; off <<= 1) {
                    s1 += __shfl_xor(s1, off);
                    s2 += __shfl_xor(s2, off);
                }
                if (lane == 0) { red[wid * 2] = s1; red[wid * 2 + 1] = s2; }
                BARRIER();
                float t1 = red[b * 4 + 0] + red[b * 4 + 2];
                float t2 = red[b * 4 + 1] + red[b * 4 + 3];
                float mu  = t1 * (1.f / 128.f);
                float var = t2 * (1.f / 128.f) - mu * mu;
                float inv = rsqrtf(var + LN_EPS);
                out[(long)(b0 + g * 4 + b) * ODIM + c] = (s - mu) * inv * gamma[c] + beta[c];
            }
            BARRIER();   // tail done before next group's dumps reuse Z
        }
    }
}

extern "C" void kernel_launch(void* const* d_in, const int* in_sizes, int n_in,
                              void* d_out, int out_size, void* d_ws, size_t ws_size,
                              hipStream_t stream) {
    const float* node_feat = (const float*)d_in[0];
    const float* time_feat = (const float*)d_in[1];
    const float* edge_feat = (const float*)d_in[2];
    const float* nbr_node  = (const float*)d_in[3];
    const float* nbr_time  = (const float*)d_in[4];
    const int*   nbr_mask  = (const int*)d_in[5];
    const float* Wq   = (const float*)d_in[6];
    const float* bq   = (const float*)d_in[7];
    const float* Wkv  = (const float*)d_in[8];
    const float* bkv  = (const float*)d_in[9];
    const float* Wo   = (const float*)d_in[10];
    const float* bo   = (const float*)d_in[11];
    const float* gma  = (const float*)d_in[12];
    const float* bta  = (const float*)d_in[13];
    float* out = (float*)d_out;

    const int B = in_sizes[0] / NDIM;  // 8192

    // workspace layout
    char* ws = (char*)d_ws;
    float* Qbuf = (float*)ws;                                   // B*128*4 = 4 MB
    unsigned short* wfrag = (unsigned short*)(ws + (size_t)B * ODIM * 4);
    unsigned short* wqT   = wfrag + WFRAG_N;
    unsigned short* woT   = wqT + WQT_N;

    hipFuncSetAttribute((const void*)ta_fused,
                        hipFuncAttributeMaxDynamicSharedMemorySize, SMEM_BYTES);

    const int prep_total = WFRAG_N + WQT_N + WOT_N;
    prep_pack<<<dim3((prep_total + 255) / 256), dim3(256), 0, stream>>>(
        Wkv, Wq, Wo, wfrag, wqT, woT);
    q_proj<<<dim3(B / 8), dim3(256), 0, stream>>>(node_feat, time_feat, wqT, bq, Qbuf);
    ta_fused<<<dim3(B / RPB), dim3(512), SMEM_BYTES, stream>>>(
        edge_feat, nbr_node, nbr_time, nbr_mask, Qbuf,
        wfrag, bkv, woT, bo, gma, bta, out);
}

// Round 19
// 153.337 us; speedup vs baseline: 3.2785x; 1.1318x over previous
//
#include <hip/hip_runtime.h>
#include <hip/hip_bf16.h>

typedef __attribute__((ext_vector_type(4))) float f32x4;
typedef __attribute__((ext_vector_type(8))) short short8;
typedef __attribute__((ext_vector_type(8))) __bf16 bf16x8;

#define NDIM 172
#define EDIM 172
#define TDIM 100
#define KCAT 444   // 172+172+100
#define QDIM 272   // 172+100
#define ODIM 128
#define ZDIM 256
#define NNBR 32
#define NPH 14     // K=32 phases (448 padded)
#define NT 7       // K=64 tiles
#define RPB 32     // batch rows per block -> grid = 256 = 1 block/CU, persistent
#define LN_EPS 1e-5f

// ---- LDS map (dynamic, ~151 KB, 1 block/CU by design) ----
#define Z_OFF    0         // Z bf16 [128][256] ZB-swizzled (4-row tail groups)
#define A_OFF    65536     // A exchange: 8 slots x 4 KB bf16 [32][64] swizzled
#define WOT_OFF  98304     // woT bf16 [128][128] k-major (32 KB)
#define QRES_OFF 131072    // [32][128] f32
#define MASK_OFF 147456    // [32][32] int
#define PB_OFF   151552    // [4][2][32] f32
#define OB_OFF   152576    // [4][128] f32
#define RED_OFF  154624    // [16][2] f32
#define SMEM_BYTES 154752

#define ZB(r,c) ((((r) * 512) + ((c) * 2)) ^ (((r) & 7) << 4))

// lgkm-only barrier: vmcnt (the deep A-load pipeline) stays in flight
#define BARRIER() do { \
    asm volatile("s_waitcnt lgkmcnt(0)\ns_barrier" ::: "memory"); \
    __builtin_amdgcn_sched_barrier(0); \
} while (0)

__device__ __forceinline__ unsigned short f2bf(float f) {
    unsigned u = __builtin_bit_cast(unsigned, f);
    u += 0x7fffu + ((u >> 16) & 1u);
    return (unsigned short)(u >> 16);
}
__device__ __forceinline__ float bf2f(unsigned short h) {
    unsigned u = ((unsigned)h) << 16;
    return __builtin_bit_cast(float, u);
}
__device__ __forceinline__ unsigned short bfb(float f) {
    return __builtin_bit_cast(unsigned short, (__bf16)f);
}

// ---- prep: wfrag = Wkv bf16 in MFMA B-fragment order (R7 layout):
// [phase 0..13][n16 0..15][lane 0..63][8]; row=n16*16+(l&15), k=phase*32+(l>>4)*8+e
#define WFRAG_N (NPH * 8192)        // 114688 shorts
#define WQT_N (QDIM * ODIM)         // 34816
#define WOT_N (ODIM * ODIM)         // 16384
__global__ void prep_pack(const float* __restrict__ Wkv, const float* __restrict__ Wq,
                          const float* __restrict__ Wo,
                          unsigned short* __restrict__ wfrag,
                          unsigned short* __restrict__ wqT,
                          unsigned short* __restrict__ woT) {
    int idx = blockIdx.x * 256 + threadIdx.x;
    if (idx < WFRAG_N) {
        int phase = idx >> 13;
        int r = idx & 8191;
        int n16 = r >> 9;
        int q = r & 511;
        int l = q >> 3, e = q & 7;
        int row = n16 * 16 + (l & 15);
        int k = phase * 32 + ((l >> 4) << 3) + e;
        wfrag[idx] = f2bf(k < KCAT ? Wkv[row * KCAT + k] : 0.f);
    } else if (idx < WFRAG_N + WQT_N) {
        int j = idx - WFRAG_N;
        int k = j >> 7, c = j & 127;
        wqT[j] = f2bf(Wq[c * QDIM + k]);
    } else if (idx < WFRAG_N + WQT_N + WOT_N) {
        int j = idx - WFRAG_N - WQT_N;
        int k = j >> 7, c = j & 127;
        woT[j] = f2bf(Wo[c * ODIM + k]);
    }
}

// ---- Q projection (unchanged, proven)
__global__ __launch_bounds__(256) void q_proj(
    const float* __restrict__ node_feat, const float* __restrict__ time_feat,
    const unsigned short* __restrict__ wqT, const float* __restrict__ bq,
    float* __restrict__ Qbuf) {
    __shared__ float x[8][QDIM];
    const int tid = threadIdx.x;
    const long b0 = (long)blockIdx.x * 8;
    for (int g = tid; g < 8 * QDIM; g += 256) {
        int r = g / QDIM, k = g - r * QDIM;
        x[r][k] = (k < NDIM) ? node_feat[(b0 + r) * NDIM + k]
                             : time_feat[(b0 + r) * TDIM + (k - NDIM)];
    }
    __syncthreads();
    const int c = tid & 127;
    const int rb = (tid >> 7) * 4;
    float s0 = bq[c], s1 = s0, s2 = s0, s3 = s0;
    #pragma unroll 8
    for (int k = 0; k < QDIM; k++) {
        float w = bf2f(wqT[k * 128 + c]);
        s0 += x[rb + 0][k] * w;
        s1 += x[rb + 1][k] * w;
        s2 += x[rb + 2][k] * w;
        s3 += x[rb + 3][k] * w;
    }
    Qbuf[(b0 + rb + 0) * 128 + c] = s0;
    Qbuf[(b0 + rb + 1) * 128 + c] = s1;
    Qbuf[(b0 + rb + 2) * 128 + c] = s2;
    Qbuf[(b0 + rb + 3) * 128 + c] = s3;
}

// ---- fused (R18 base): W in registers, A reg-pipelined 7 deep, persistent
// blocks. NEW: 4-tile barrier windows (2 barriers/ri over 8 rotating slots)
// + woT cached in LDS for the out-proj tail.
__global__ __launch_bounds__(512, 2) void ta_fused(
    const float* __restrict__ edge_feat, const float* __restrict__ nbr_node,
    const float* __restrict__ nbr_time, const int* __restrict__ nbr_mask,
    const float* __restrict__ Qbuf,
    const unsigned short* __restrict__ wfrag, const float* __restrict__ bkv,
    const unsigned short* __restrict__ woT, const float* __restrict__ bo,
    const float* __restrict__ gamma, const float* __restrict__ beta,
    float* __restrict__ out)
{
    extern __shared__ __align__(16) unsigned char smem[];
    float* qresL = (float*)(smem + QRES_OFF);
    int*   maskL = (int*)(smem + MASK_OFF);
    float* Pband = (float*)(smem + PB_OFF);
    float* Obuf  = (float*)(smem + OB_OFF);
    float* red   = (float*)(smem + RED_OFF);
    unsigned short* woL = (unsigned short*)(smem + WOT_OFF);

    const int tid  = threadIdx.x;
    const int lane = tid & 63;
    const int wid  = tid >> 6;          // 0..7 = 32-col band
    const int b0   = blockIdx.x * RPB;

    // ---- stage masks + Q rows + woT for the persistent block (one-time)
    for (int i = tid; i < RPB * NNBR; i += 512)
        maskL[i] = nbr_mask[(long)b0 * NNBR + i];
    for (int i = tid; i < RPB * ODIM; i += 512)
        qresL[i] = Qbuf[(long)b0 * ODIM + i];
    #pragma unroll
    for (int i = 0; i < 4; i++)   // 16384 shorts = 2048 uint4
        ((uint4*)woL)[i * 512 + tid] = ((const uint4*)woT)[i * 512 + tid];
    __syncthreads();   // one-time full drain, nothing deep in flight yet

    // ---- W fragments into registers (one-time; read-only, literal indices)
    bf16x8 Wr[2 * NPH];
    #pragma unroll
    for (int p = 0; p < NPH; p++)
        #pragma unroll
        for (int j = 0; j < 2; j++)
            Wr[p * 2 + j] = __builtin_bit_cast(bf16x8,
                *(const short8*)(wfrag + ((size_t)(p * 16 + wid * 2 + j) * 512 + lane * 8)));
    const float bk0 = bkv[wid * 32 + (lane & 15)];
    const float bk1 = bkv[wid * 32 + 16 + (lane & 15)];

    // ---- per-thread A geometry: thread = (rowA 0..31, kgrp 0..15)
    const int rowA  = tid >> 4;
    const int kgrp4 = (tid & 15) * 4;
    const int awb   = ((rowA * 128 + (tid & 15) * 8) ^ ((rowA & 7) << 4));

    // Branch-free A addressing: per-thread pointer + stride tables
    const float* aptr[NT];
    int astr[NT];
    #pragma unroll
    for (int t = 0; t < NT; t++) {
        int k = t * 64 + kgrp4;
        long rg = (long)b0 * NNBR + rowA;
        if (k < NDIM) {
            aptr[t] = nbr_node + rg * NDIM + k;
            astr[t] = NNBR * NDIM;
        } else if (k < NDIM + EDIM) {
            aptr[t] = edge_feat + rg * EDIM + (k - NDIM);
            astr[t] = NNBR * EDIM;
        } else {
            int off = k - NDIM - EDIM;
            if (off > TDIM - 4) off = TDIM - 4;   // pad: garbage x W=0
            aptr[t] = nbr_time + rg * TDIM + off;
            astr[t] = NNBR * TDIM;
        }
    }

    // ---- prologue: iteration 0's 7 tiles in flight (the latency buffer)
    float4 rs[NT];
    #pragma unroll
    for (int t = 0; t < NT; t++) {
        rs[t] = *(const float4*)aptr[t];
        aptr[t] += astr[t];
    }
    __builtin_amdgcn_sched_barrier(0);

    for (int ri = 0; ri < RPB; ri++) {
        const int tb = ri * NT;         // rolling slot counter base
        f32x4 acc[2][2];
        #pragma unroll
        for (int m = 0; m < 2; m++)
            #pragma unroll
            for (int n = 0; n < 2; n++) acc[m][n] = (f32x4){0.f, 0.f, 0.f, 0.f};

        #pragma unroll
        for (int w = 0; w < 2; w++) {   // windows {0,1,2,3} and {4,5,6}
            const int t0 = w * 4;
            const int ntw = w ? 3 : 4;
            // stage window's tiles (loads issued ~1 ri ago -> counted wait)
            #pragma unroll
            for (int tt = 0; tt < 4; tt++) {
                if (tt < ntw) {
                    const int t = t0 + tt;
                    unsigned char* aw = smem + A_OFF + (((tb + t) & 7) << 12);
                    float4 v = rs[t];
                    uint2 u;
                    u.x = (unsigned)bfb(v.x) | ((unsigned)bfb(v.y) << 16);
                    u.y = (unsigned)bfb(v.z) | ((unsigned)bfb(v.w) << 16);
                    *(uint2*)(aw + awb) = u;
                }
            }
            // rolling refill: iter ri+1, same tiles
            if (ri + 1 < RPB) {
                #pragma unroll
                for (int tt = 0; tt < 4; tt++) {
                    if (tt < ntw) {
                        const int t = t0 + tt;
                        rs[t] = *(const float4*)aptr[t];
                        aptr[t] += astr[t];
                    }
                }
            }
            __builtin_amdgcn_sched_barrier(0);
            BARRIER();                   // exchange visible; vmem stays in flight
            // compute window (W from registers)
            __builtin_amdgcn_s_setprio(1);
            #pragma unroll
            for (int tt = 0; tt < 4; tt++) {
                if (tt < ntw) {
                    const int t = t0 + tt;
                    const unsigned char* aw = smem + A_OFF + (((tb + t) & 7) << 12);
                    #pragma unroll
                    for (int kk = 0; kk < 2; kk++) {
                        bf16x8 af[2];
                        #pragma unroll
                        for (int m = 0; m < 2; m++) {
                            int row = m * 16 + (lane & 15);
                            af[m] = __builtin_bit_cast(bf16x8, *(const short8*)(
                                aw + row * 128 + ((kk * 64 + (lane >> 4) * 16) ^ ((row & 7) << 4))));
                        }
                        const int p = t * 2 + kk;
                        acc[0][0] = __builtin_amdgcn_mfma_f32_16x16x32_bf16(af[0], Wr[p*2+0], acc[0][0], 0, 0, 0);
                        acc[0][1] = __builtin_amdgcn_mfma_f32_16x16x32_bf16(af[0], Wr[p*2+1], acc[0][1], 0, 0, 0);
                        acc[1][0] = __builtin_amdgcn_mfma_f32_16x16x32_bf16(af[1], Wr[p*2+0], acc[1][0], 0, 0, 0);
                        acc[1][1] = __builtin_amdgcn_mfma_f32_16x16x32_bf16(af[1], Wr[p*2+1], acc[1][1], 0, 0, 0);
                    }
                }
            }
            __builtin_amdgcn_s_setprio(0);
        }

        // ---- dump Z row-block (+bkv); C/D: col=lane&15, row=(lane>>4)*4+j
        const int gi = ri & 3;
        #pragma unroll
        for (int n = 0; n < 2; n++) {
            int col = wid * 32 + n * 16 + (lane & 15);
            float bk = n ? bk1 : bk0;
            #pragma unroll
            for (int m = 0; m < 2; m++)
                #pragma unroll
                for (int j = 0; j < 4; j++) {
                    int rowZ = gi * 32 + m * 16 + (lane >> 4) * 4 + j;
                    *(unsigned short*)(smem + ZB(rowZ, col)) = bfb(acc[m][n][j] + bk);
                }
        }

        if (gi == 3) {
            const int g = ri >> 2;             // tail group 0..7 (uniform)
            BARRIER();                          // dumps visible; A loads keep flying

            // ---- scores + softmax: waves 0..7 -> (bl=wid>>1, h=wid&1)
            {
                int bl = wid >> 1, h = wid & 1;
                int n2 = lane >> 1, half = lane & 1;
                int np = h * 16 + (n2 >> 1);
                int rowZ = bl * NNBR + np;
                int cb = (n2 & 1) * 64 + half * 32;
                const float* q = qresL + (g * 4 + bl) * ODIM + h * 64 + half * 32;
                float s = 0.f;
                #pragma unroll
                for (int j = 0; j < 4; j++) {
                    short8 z8 = *(const short8*)(smem + ZB(rowZ, cb + j * 8));
                    #pragma unroll
                    for (int e = 0; e < 8; e++)
                        s += q[j * 8 + e] * bf2f((unsigned short)z8[e]);
                }
                s += __shfl_xor(s, 1);
                s *= 0.125f;
                if (maskL[(g * 4 + bl) * NNBR + n2] == 0) s = -1e10f;
                float mx = s;
                #pragma unroll
                for (int off = 1; off < 64; off <<= 1) mx = fmaxf(mx, __shfl_xor(mx, off));
                float e = __expf(s - mx);
                float sum = e;
                #pragma unroll
                for (int off = 1; off < 64; off <<= 1) sum += __shfl_xor(sum, off);
                float pv = e * 2.f / sum;
                if (half == 0) Pband[(bl * 2 + h) * NNBR + n2] = pv;
            }
            BARRIER();

            // ---- O = P @ V
            {
                int b = tid >> 7, c = tid & 127, h = c >> 6, d = c & 63;
                const float* P = Pband + (b * 2 + h) * NNBR;
                float s = 0.f;
                #pragma unroll
                for (int n2 = 0; n2 < NNBR; n2++) {
                    int np = h * 16 + (n2 >> 1);
                    int col = ODIM + (n2 & 1) * 64 + d;
                    s += P[n2] * bf2f(*(const unsigned short*)(smem + ZB(b * NNBR + np, col)));
                }
                Obuf[b * ODIM + c] = s;
            }
            BARRIER();

            // ---- out proj (woT from LDS, conflict-free k-major) + LayerNorm
            {
                int b = tid >> 7, c = tid & 127;
                float s = bo[c];
                const float* ob = Obuf + b * ODIM;
                #pragma unroll 8
                for (int k = 0; k < ODIM; k++)
                    s += ob[k] * bf2f(woL[k * 128 + c]);
                float s1 = s, s2 = s * s;
                #pragma unroll
                for (int off = 1; off < 64; off <<= 1) {
                    s1 += __shfl_xor(s1, off);
                    s2 += __shfl_xor(s2, off);
                }
                if (lane == 0) { red[wid * 2] = s1; red[wid * 2 + 1] = s2; }
                BARRIER();
                float t1 = red[b * 4 + 0] + red[b * 4 + 2];
                float t2 = red[b * 4 + 1] + red[b * 4 + 3];
                float mu  = t1 * (1.f / 128.f);
                float var = t2 * (1.f / 128.f) - mu * mu;
                float inv = rsqrtf(var + LN_EPS);
                out[(long)(b0 + g * 4 + b) * ODIM + c] = (s - mu) * inv * gamma[c] + beta[c];
            }
            BARRIER();   // tail done before next group's dumps reuse Z
        }
    }
}

extern "C" void kernel_launch(void* const* d_in, const int* in_sizes, int n_in,
                              void* d_out, int out_size, void* d_ws, size_t ws_size,
                              hipStream_t stream) {
    const float* node_feat = (const float*)d_in[0];
    const float* time_feat = (const float*)d_in[1];
    const float* edge_feat = (const float*)d_in[2];
    const float* nbr_node  = (const float*)d_in[3];
    const float* nbr_time  = (const float*)d_in[4];
    const int*   nbr_mask  = (const int*)d_in[5];
    const float* Wq   = (const float*)d_in[6];
    const float* bq   = (const float*)d_in[7];
    const float* Wkv  = (const float*)d_in[8];
    const float* bkv  = (const float*)d_in[9];
    const float* Wo   = (const float*)d_in[10];
    const float* bo   = (const float*)d_in[11];
    const float* gma  = (const float*)d_in[12];
    const float* bta  = (const float*)d_in[13];
    float* out = (float*)d_out;

    const int B = in_sizes[0] / NDIM;  // 8192

    // workspace layout
    char* ws = (char*)d_ws;
    float* Qbuf = (float*)ws;                                   // B*128*4 = 4 MB
    unsigned short* wfrag = (unsigned short*)(ws + (size_t)B * ODIM * 4);
    unsigned short* wqT   = wfrag + WFRAG_N;
    unsigned short* woT   = wqT + WQT_N;

    hipFuncSetAttribute((const void*)ta_fused,
                        hipFuncAttributeMaxDynamicSharedMemorySize, SMEM_BYTES);

    const int prep_total = WFRAG_N + WQT_N + WOT_N;
    prep_pack<<<dim3((prep_total + 255) / 256), dim3(256), 0, stream>>>(
        Wkv, Wq, Wo, wfrag, wqT, woT);
    q_proj<<<dim3(B / 8), dim3(256), 0, stream>>>(node_feat, time_feat, wqT, bq, Qbuf);
    ta_fused<<<dim3(B / RPB), dim3(512), SMEM_BYTES, stream>>>(
        edge_feat, nbr_node, nbr_time, nbr_mask, Qbuf,
        wfrag, bkv, woT, bo, gma, bta, out);
}

// Round 20
// 147.188 us; speedup vs baseline: 3.4155x; 1.0418x over previous
//
#include <hip/hip_runtime.h>
#include <hip/hip_bf16.h>

typedef __attribute__((ext_vector_type(4))) float f32x4;
typedef __attribute__((ext_vector_type(8))) short short8;
typedef __attribute__((ext_vector_type(8))) __bf16 bf16x8;

#define NDIM 172
#define EDIM 172
#define TDIM 100
#define KCAT 444   // 172+172+100
#define QDIM 272   // 172+100
#define ODIM 128
#define ZDIM 256
#define NNBR 32
#define NPH 14     // K=32 phases (448 padded)
#define NT 7       // K=64 tiles
#define RPB 32     // batch rows per block -> grid = 256 = 1 block/CU, persistent
#define LN_EPS 1e-5f

// ---- LDS map (dynamic, ~148 KB, 1 block/CU by design) ----
#define Z_OFF    0         // Z bf16 [128][256] ZB-swizzled (4-row tail groups)
#define A_OFF    65536     // A exchange: single 7-tile slab (28 KB)
#define WOC_OFF  94208     // Wo bf16 c-major, 272 B row pitch (34816 B)
#define QRES_OFF 129024    // [32][128] f32
#define MASK_OFF 145408    // [32][32] int
#define OB_OFF   149504    // [4][128] f32
#define RED_OFF  151552    // [16][2] f32
#define SMEM_BYTES 151680

#define ZB(r,c) ((((r) * 512) + ((c) * 2)) ^ (((r) & 7) << 4))

// lgkm-only barrier: vmcnt (the deep A-load pipeline) stays in flight
#define BARRIER() do { \
    asm volatile("s_waitcnt lgkmcnt(0)\ns_barrier" ::: "memory"); \
    __builtin_amdgcn_sched_barrier(0); \
} while (0)

__device__ __forceinline__ unsigned short f2bf(float f) {
    unsigned u = __builtin_bit_cast(unsigned, f);
    u += 0x7fffu + ((u >> 16) & 1u);
    return (unsigned short)(u >> 16);
}
__device__ __forceinline__ float bf2f(unsigned short h) {
    unsigned u = ((unsigned)h) << 16;
    return __builtin_bit_cast(float, u);
}
__device__ __forceinline__ unsigned short bfb(float f) {
    return __builtin_bit_cast(unsigned short, (__bf16)f);
}

// ---- prep: wfrag = Wkv bf16 in MFMA B-fragment order (R7 layout):
// [phase 0..13][n16 0..15][lane 0..63][8]; row=n16*16+(l&15), k=phase*32+(l>>4)*8+e
#define WFRAG_N (NPH * 8192)        // 114688 shorts
#define WQT_N (QDIM * ODIM)         // 34816
#define WOT_N (ODIM * ODIM)         // 16384
__global__ void prep_pack(const float* __restrict__ Wkv, const float* __restrict__ Wq,
                          const float* __restrict__ Wo,
                          unsigned short* __restrict__ wfrag,
                          unsigned short* __restrict__ wqT,
                          unsigned short* __restrict__ woT) {
    int idx = blockIdx.x * 256 + threadIdx.x;
    if (idx < WFRAG_N) {
        int phase = idx >> 13;
        int r = idx & 8191;
        int n16 = r >> 9;
        int q = r & 511;
        int l = q >> 3, e = q & 7;
        int row = n16 * 16 + (l & 15);
        int k = phase * 32 + ((l >> 4) << 3) + e;
        wfrag[idx] = f2bf(k < KCAT ? Wkv[row * KCAT + k] : 0.f);
    } else if (idx < WFRAG_N + WQT_N) {
        int j = idx - WFRAG_N;
        int k = j >> 7, c = j & 127;
        wqT[j] = f2bf(Wq[c * QDIM + k]);
    } else if (idx < WFRAG_N + WQT_N + WOT_N) {
        int j = idx - WFRAG_N - WQT_N;
        int k = j >> 7, c = j & 127;
        woT[j] = f2bf(Wo[c * ODIM + k]);
    }
}

// ---- Q projection (unchanged, proven)
__global__ __launch_bounds__(256) void q_proj(
    const float* __restrict__ node_feat, const float* __restrict__ time_feat,
    const unsigned short* __restrict__ wqT, const float* __restrict__ bq,
    float* __restrict__ Qbuf) {
    __shared__ float x[8][QDIM];
    const int tid = threadIdx.x;
    const long b0 = (long)blockIdx.x * 8;
    for (int g = tid; g < 8 * QDIM; g += 256) {
        int r = g / QDIM, k = g - r * QDIM;
        x[r][k] = (k < NDIM) ? node_feat[(b0 + r) * NDIM + k]
                             : time_feat[(b0 + r) * TDIM + (k - NDIM)];
    }
    __syncthreads();
    const int c = tid & 127;
    const int rb = (tid >> 7) * 4;
    float s0 = bq[c], s1 = s0, s2 = s0, s3 = s0;
    #pragma unroll 8
    for (int k = 0; k < QDIM; k++) {
        float w = bf2f(wqT[k * 128 + c]);
        s0 += x[rb + 0][k] * w;
        s1 += x[rb + 1][k] * w;
        s2 += x[rb + 2][k] * w;
        s3 += x[rb + 3][k] * w;
    }
    Qbuf[(b0 + rb + 0) * 128 + c] = s0;
    Qbuf[(b0 + rb + 1) * 128 + c] = s1;
    Qbuf[(b0 + rb + 2) * 128 + c] = s2;
    Qbuf[(b0 + rb + 3) * 128 + c] = s3;
}

// ---- fused (R19 base): W in registers, A reg-pipelined 7 deep, persistent
// blocks. NEW: single 7-tile window (fixed slab), fused scores+PV (no Pband,
// -2 tail barriers), vectorized out-proj from LDS (c-major, 272B pitch).
__global__ __launch_bounds__(512, 2) void ta_fused(
    const float* __restrict__ edge_feat, const float* __restrict__ nbr_node,
    const float* __restrict__ nbr_time, const int* __restrict__ nbr_mask,
    const float* __restrict__ Qbuf,
    const unsigned short* __restrict__ wfrag, const float* __restrict__ bkv,
    const unsigned short* __restrict__ woT, const float* __restrict__ bo,
    const float* __restrict__ gamma, const float* __restrict__ beta,
    float* __restrict__ out)
{
    extern __shared__ __align__(16) unsigned char smem[];
    float* qresL = (float*)(smem + QRES_OFF);
    int*   maskL = (int*)(smem + MASK_OFF);
    float* Obuf  = (float*)(smem + OB_OFF);
    float* red   = (float*)(smem + RED_OFF);

    const int tid  = threadIdx.x;
    const int lane = tid & 63;
    const int wid  = tid >> 6;          // 0..7 = 32-col band
    const int b0   = blockIdx.x * RPB;

    // ---- one-time staging: masks, Q rows, Wo (c-major, 272B pitch)
    for (int i = tid; i < RPB * NNBR; i += 512)
        maskL[i] = nbr_mask[(long)b0 * NNBR + i];
    for (int i = tid; i < RPB * ODIM; i += 512)
        qresL[i] = Qbuf[(long)b0 * ODIM + i];
    for (int i = tid; i < WOT_N; i += 512) {
        int k = i >> 7, c = i & 127;
        *(unsigned short*)(smem + WOC_OFF + c * 272 + k * 2) = woT[i];
    }
    __syncthreads();   // one-time full drain, nothing deep in flight yet

    // ---- W fragments into registers (one-time; read-only, literal indices)
    bf16x8 Wr[2 * NPH];
    #pragma unroll
    for (int p = 0; p < NPH; p++)
        #pragma unroll
        for (int j = 0; j < 2; j++)
            Wr[p * 2 + j] = __builtin_bit_cast(bf16x8,
                *(const short8*)(wfrag + ((size_t)(p * 16 + wid * 2 + j) * 512 + lane * 8)));
    const float bk0 = bkv[wid * 32 + (lane & 15)];
    const float bk1 = bkv[wid * 32 + 16 + (lane & 15)];
    const float boR = bo[tid & 127];
    const float gmR = gamma[tid & 127];
    const float btR = beta[tid & 127];

    // ---- per-thread A geometry: thread = (rowA 0..31, kgrp 0..15)
    const int rowA  = tid >> 4;
    const int kgrp4 = (tid & 15) * 4;
    const int awb   = ((rowA * 128 + (tid & 15) * 8) ^ ((rowA & 7) << 4));

    // Branch-free A addressing: per-thread pointer + stride tables
    const float* aptr[NT];
    int astr[NT];
    #pragma unroll
    for (int t = 0; t < NT; t++) {
        int k = t * 64 + kgrp4;
        long rg = (long)b0 * NNBR + rowA;
        if (k < NDIM) {
            aptr[t] = nbr_node + rg * NDIM + k;
            astr[t] = NNBR * NDIM;
        } else if (k < NDIM + EDIM) {
            aptr[t] = edge_feat + rg * EDIM + (k - NDIM);
            astr[t] = NNBR * EDIM;
        } else {
            int off = k - NDIM - EDIM;
            if (off > TDIM - 4) off = TDIM - 4;   // pad: garbage x W=0
            aptr[t] = nbr_time + rg * TDIM + off;
            astr[t] = NNBR * TDIM;
        }
    }

    // ---- prologue: iteration 0's 7 tiles in flight (the latency buffer)
    float4 rs[NT];
    #pragma unroll
    for (int t = 0; t < NT; t++) {
        rs[t] = *(const float4*)aptr[t];
        aptr[t] += astr[t];
    }
    __builtin_amdgcn_sched_barrier(0);

    for (int ri = 0; ri < RPB; ri++) {
        f32x4 acc[2][2];
        #pragma unroll
        for (int m = 0; m < 2; m++)
            #pragma unroll
            for (int n = 0; n < 2; n++) acc[m][n] = (f32x4){0.f, 0.f, 0.f, 0.f};

        // ---- stage all 7 tiles (loads issued last ri -> counted vmcnt wait)
        #pragma unroll
        for (int t = 0; t < NT; t++) {
            float4 v = rs[t];
            uint2 u;
            u.x = (unsigned)bfb(v.x) | ((unsigned)bfb(v.y) << 16);
            u.y = (unsigned)bfb(v.z) | ((unsigned)bfb(v.w) << 16);
            *(uint2*)(smem + A_OFF + t * 4096 + awb) = u;
        }
        // rolling refill: iter ri+1, all tiles
        if (ri + 1 < RPB) {
            #pragma unroll
            for (int t = 0; t < NT; t++) {
                rs[t] = *(const float4*)aptr[t];
                aptr[t] += astr[t];
            }
        }
        __builtin_amdgcn_sched_barrier(0);
        BARRIER();                       // slab visible; vmem stays in flight

        // ---- compute all 7 tiles (W from registers)
        __builtin_amdgcn_s_setprio(1);
        #pragma unroll
        for (int t = 0; t < NT; t++) {
            const unsigned char* aw = smem + A_OFF + t * 4096;
            #pragma unroll
            for (int kk = 0; kk < 2; kk++) {
                bf16x8 af[2];
                #pragma unroll
                for (int m = 0; m < 2; m++) {
                    int row = m * 16 + (lane & 15);
                    af[m] = __builtin_bit_cast(bf16x8, *(const short8*)(
                        aw + row * 128 + ((kk * 64 + (lane >> 4) * 16) ^ ((row & 7) << 4))));
                }
                const int p = t * 2 + kk;
                acc[0][0] = __builtin_amdgcn_mfma_f32_16x16x32_bf16(af[0], Wr[p*2+0], acc[0][0], 0, 0, 0);
                acc[0][1] = __builtin_amdgcn_mfma_f32_16x16x32_bf16(af[0], Wr[p*2+1], acc[0][1], 0, 0, 0);
                acc[1][0] = __builtin_amdgcn_mfma_f32_16x16x32_bf16(af[1], Wr[p*2+0], acc[1][0], 0, 0, 0);
                acc[1][1] = __builtin_amdgcn_mfma_f32_16x16x32_bf16(af[1], Wr[p*2+1], acc[1][1], 0, 0, 0);
            }
        }
        __builtin_amdgcn_s_setprio(0);

        // ---- dump Z row-block (+bkv); C/D: col=lane&15, row=(lane>>4)*4+j
        const int gi = ri & 3;
        #pragma unroll
        for (int n = 0; n < 2; n++) {
            int col = wid * 32 + n * 16 + (lane & 15);
            float bk = n ? bk1 : bk0;
            #pragma unroll
            for (int m = 0; m < 2; m++)
                #pragma unroll
                for (int j = 0; j < 4; j++) {
                    int rowZ = gi * 32 + m * 16 + (lane >> 4) * 4 + j;
                    *(unsigned short*)(smem + ZB(rowZ, col)) = bfb(acc[m][n][j] + bk);
                }
        }
        BARRIER();   // slab free for next stage; dumps visible; vmem in flight

        if (gi == 3) {
            const int g = ri >> 2;             // tail group 0..7 (uniform)

            // ---- fused scores + softmax + PV: wave (bl=wid>>1, h=wid&1)
            {
                int bl = wid >> 1, h = wid & 1;
                int n2 = lane >> 1, half = lane & 1;
                int np = h * 16 + (n2 >> 1);
                int rowZ = bl * NNBR + np;
                int cb = (n2 & 1) * 64 + half * 32;
                const float* q = qresL + (g * 4 + bl) * ODIM + h * 64 + half * 32;
                float s = 0.f;
                #pragma unroll
                for (int j = 0; j < 4; j++) {
                    short8 z8 = *(const short8*)(smem + ZB(rowZ, cb + j * 8));
                    #pragma unroll
                    for (int e = 0; e < 8; e++)
                        s += q[j * 8 + e] * bf2f((unsigned short)z8[e]);
                }
                s += __shfl_xor(s, 1);
                s *= 0.125f;
                if (maskL[(g * 4 + bl) * NNBR + n2] == 0) s = -1e10f;
                float mx = s;
                #pragma unroll
                for (int off = 1; off < 64; off <<= 1) mx = fmaxf(mx, __shfl_xor(mx, off));
                float e = __expf(s - mx);
                float sum = e;
                #pragma unroll
                for (int off = 1; off < 64; off <<= 1) sum += __shfl_xor(sum, off);
                float pv = e * 2.f / sum;   // each n2 counted twice in sum

                // PV in-wave: lane d computes O[bl][h*64+d]
                int d = lane;
                float o = 0.f;
                #pragma unroll
                for (int n = 0; n < NNBR; n++) {
                    float p = __shfl(pv, n * 2);
                    int npn = h * 16 + (n >> 1);
                    int col = ODIM + (n & 1) * 64 + d;
                    o += p * bf2f(*(const unsigned short*)(smem + ZB(bl * NNBR + npn, col)));
                }
                Obuf[bl * ODIM + h * 64 + d] = o;
            }
            BARRIER();

            // ---- out proj (vectorized c-major Wo from LDS) + LayerNorm
            {
                int b = tid >> 7, c = tid & 127;
                float s = boR;
                const float* ob = Obuf + b * ODIM;
                const unsigned char* wrow = smem + WOC_OFF + c * 272;
                #pragma unroll
                for (int j = 0; j < 16; j++) {
                    short8 w8 = *(const short8*)(wrow + j * 16);
                    float4 o0 = *(const float4*)(ob + j * 8);
                    float4 o1 = *(const float4*)(ob + j * 8 + 4);
                    s += o0.x * bf2f((unsigned short)w8[0]) + o0.y * bf2f((unsigned short)w8[1])
                       + o0.z * bf2f((unsigned short)w8[2]) + o0.w * bf2f((unsigned short)w8[3])
                       + o1.x * bf2f((unsigned short)w8[4]) + o1.y * bf2f((unsigned short)w8[5])
                       + o1.z * bf2f((unsigned short)w8[6]) + o1.w * bf2f((unsigned short)w8[7]);
                }
                float s1 = s, s2 = s * s;
                #pragma unroll
                for (int off = 1; off < 64; off <<= 1) {
                    s1 += __shfl_xor(s1, off);
                    s2 += __shfl_xor(s2, off);
                }
                if (lane == 0) { red[wid * 2] = s1; red[wid * 2 + 1] = s2; }
                BARRIER();
                float t1 = red[b * 4 + 0] + red[b * 4 + 2];
                float t2 = red[b * 4 + 1] + red[b * 4 + 3];
                float mu  = t1 * (1.f / 128.f);
                float var = t2 * (1.f / 128.f) - mu * mu;
                float inv = rsqrtf(var + LN_EPS);
                out[(long)(b0 + g * 4 + b) * ODIM + c] = (s - mu) * inv * gmR + btR;
            }
            // no end barrier: next Z-dump is >=2 barriers downstream
        }
    }
}

extern "C" void kernel_launch(void* const* d_in, const int* in_sizes, int n_in,
                              void* d_out, int out_size, void* d_ws, size_t ws_size,
                              hipStream_t stream) {
    const float* node_feat = (const float*)d_in[0];
    const float* time_feat = (const float*)d_in[1];
    const float* edge_feat = (const float*)d_in[2];
    const float* nbr_node  = (const float*)d_in[3];
    const float* nbr_time  = (const float*)d_in[4];
    const int*   nbr_mask  = (const int*)d_in[5];
    const float* Wq   = (const float*)d_in[6];
    const float* bq   = (const float*)d_in[7];
    const float* Wkv  = (const float*)d_in[8];
    const float* bkv  = (const float*)d_in[9];
    const float* Wo   = (const float*)d_in[10];
    const float* bo   = (const float*)d_in[11];
    const float* gma  = (const float*)d_in[12];
    const float* bta  = (const float*)d_in[13];
    float* out = (float*)d_out;

    const int B = in_sizes[0] / NDIM;  // 8192

    // workspace layout
    char* ws = (char*)d_ws;
    float* Qbuf = (float*)ws;                                   // B*128*4 = 4 MB
    unsigned short* wfrag = (unsigned short*)(ws + (size_t)B * ODIM * 4);
    unsigned short* wqT   = wfrag + WFRAG_N;
    unsigned short* woT   = wqT + WQT_N;

    hipFuncSetAttribute((const void*)ta_fused,
                        hipFuncAttributeMaxDynamicSharedMemorySize, SMEM_BYTES);

    const int prep_total = WFRAG_N + WQT_N + WOT_N;
    prep_pack<<<dim3((prep_total + 255) / 256), dim3(256), 0, stream>>>(
        Wkv, Wq, Wo, wfrag, wqT, woT);
    q_proj<<<dim3(B / 8), dim3(256), 0, stream>>>(node_feat, time_feat, wqT, bq, Qbuf);
    ta_fused<<<dim3(B / RPB), dim3(512), SMEM_BYTES, stream>>>(
        edge_feat, nbr_node, nbr_time, nbr_mask, Qbuf,
        wfrag, bkv, woT, bo, gma, bta, out);
}